// Round 8
// baseline (2203.283 us; speedup 1.0000x reference)
//
#include <hip/hip_runtime.h>
#include <hip/hip_bf16.h>
#include <math.h>

#define BB 32
#define LSN 256
#define LTN 128
#define CCH 768
#define NHH 12
#define NTOK 384
#define NKEEP 180
#define NREM 76
#define NNEW 308
#define MS 8192    /* B*LS */
#define MN 9856    /* B*NNEW */

typedef unsigned short u16;
typedef __attribute__((ext_vector_type(8))) short s8v;
typedef __attribute__((ext_vector_type(4))) float f4v;
typedef __attribute__((ext_vector_type(2))) float f2v;

__device__ __forceinline__ u16 f2bf(float x) {
    union { __hip_bfloat16 b; u16 u; } c; c.b = __float2bfloat16(x); return c.u;
}
__device__ __forceinline__ float bf2f(u16 u) {
    return __uint_as_float(((unsigned)u) << 16);
}
__device__ __forceinline__ void gl_lds16(const u16* g, u16* l) {
    __builtin_amdgcn_global_load_lds((const __attribute__((address_space(1))) unsigned*)g,
                                     (__attribute__((address_space(3))) unsigned*)l, 16, 0, 0);
}

__global__ void k_fail(float* o, float v) { o[0] = v; }

// ================= exact head (same FP ops/order as round 3 — bit-exact sort keys) =================
__global__ void k_reps(const float* __restrict__ x, const float* __restrict__ mask,
                       float* __restrict__ rep0, float* __restrict__ rep1) {
    int b = blockIdx.x, t = threadIdx.x;
    for (int c = t; c < CCH; c += 256) {
        float m0 = -INFINITY, m1 = -INFINITY;
        for (int i = 0; i < 64; ++i) {
            float v0 = x[(size_t)(b * NTOK + i) * CCH + c] * mask[b * 64 + i];
            float v1 = x[(size_t)(b * NTOK + 64 + i) * CCH + c] * mask[BB * 64 + b * 64 + i];
            m0 = fmaxf(m0, v0); m1 = fmaxf(m1, v1);
        }
        rep0[b * CCH + c] = m0; rep1[b * CCH + c] = m1;
    }
}

__device__ __forceinline__ float gelu_np(float v) {
    float t = v / 1.4142135623730951f;
    float ef = (float)erf((double)t);
    return 0.5f * v * (1.0f + ef);
}

// Exact-head GEMM, register/SGPR variant.
// Block = 64 rows x 64 cols; wave w owns all 64 rows x 16 cols (col base wave-uniform
// => B loads are scalar s_loads, no LDS for B). A in LDS [k][row]: 1 ds_read_b32 feeds
// 16 FMAs (8 v_pk_fma_f32). Per-output k-chain strictly ascending, one accumulator
// => bit-identical to round-3 head. Grid XCD-swizzled: all col-blocks of a row band
// land on one XCD (A served from that XCD's L2).
template<int ROWMAP>
__global__ __launch_bounds__(256) void gemm_head_reg(const float* __restrict__ A,
                                                     const float* __restrict__ rep0, const float* __restrict__ rep1,
                                                     const float* __restrict__ W, const float* __restrict__ bias,
                                                     float* __restrict__ out, int N, int K, int ncol) {
    __shared__ float As[32][64];
    int t = threadIdx.x, lane = t & 63, wid = t >> 6;
    int id = blockIdx.x;
    int r = id & 7, q = id >> 3;
    int qd = q / ncol;
    int band = r + 8 * qd, col = q - ncol * qd;
    int bm = band * 64, bn = col * 64;
    int b = bm >> 8;
    int colu = __builtin_amdgcn_readfirstlane(bn + wid * 16);

    f2v acc2[8];
#pragma unroll
    for (int j = 0; j < 8; ++j) acc2[j] = (f2v){0.f, 0.f};

    // staging: thread covers row=t>>2, k in [kof, kof+8)
    int srow = t >> 2, kof = (t & 3) * 8;
    size_t aoff;
    if (ROWMAP) aoff = (size_t)(b * NTOK + LTN + ((bm + srow) & 255)) * CCH;
    else        aoff = (size_t)(bm + srow) * K;

#define LOADA(kg) (ROWMAP ? (((kg) < CCH) ? *(const float4*)&A[aoff + (kg)] \
                    : (((kg) < 2*CCH) ? *(const float4*)&rep0[b*CCH + (kg) - CCH] \
                                      : *(const float4*)&rep1[b*CCH + (kg) - 2*CCH])) \
                   : *(const float4*)&A[aoff + (kg)])

    int nt = K >> 5;
    float4 ra0 = LOADA(kof), ra1 = LOADA(kof + 4);

    for (int tile = 0; tile < nt; ++tile) {
        int k0 = tile << 5;
        __syncthreads();   // previous tile's readers done
        As[kof + 0][srow] = ra0.x; As[kof + 1][srow] = ra0.y;
        As[kof + 2][srow] = ra0.z; As[kof + 3][srow] = ra0.w;
        As[kof + 4][srow] = ra1.x; As[kof + 5][srow] = ra1.y;
        As[kof + 6][srow] = ra1.z; As[kof + 7][srow] = ra1.w;
        if (tile + 1 < nt) {
            ra0 = LOADA(k0 + 32 + kof); ra1 = LOADA(k0 + 32 + kof + 4);
        }
        __syncthreads();
#pragma unroll
        for (int k = 0; k < 32; ++k) {
            float a = As[k][lane];
            const float* Wk = W + (size_t)(k0 + k) * N + colu;
            f2v av = {a, a};
#pragma unroll
            for (int j = 0; j < 8; ++j) {
                f2v bv = *(const f2v*)(Wk + 2 * j);
                acc2[j] = __builtin_elementwise_fma(av, bv, acc2[j]);
            }
        }
    }
#undef LOADA

    // epilogue: bias + gelu, 16 floats per lane
    int m = bm + lane;
    float o[16];
#pragma unroll
    for (int j = 0; j < 8; ++j) {
        o[2 * j + 0] = gelu_np(acc2[j][0] + bias[colu + 2 * j + 0]);
        o[2 * j + 1] = gelu_np(acc2[j][1] + bias[colu + 2 * j + 1]);
    }
    float* dst = out + (size_t)m * N + colu;
#pragma unroll
    for (int j = 0; j < 4; ++j)
        *(float4*)(dst + 4 * j) = *(const float4*)&o[4 * j];
}

__global__ void k_d4(const float* __restrict__ h3, const float* __restrict__ w4,
                     const float* __restrict__ b4, float* __restrict__ probs) {
    int m = blockIdx.x * 256 + threadIdx.x;
    if (m >= MS) return;
    float acc = 0.f;
    for (int k = 0; k < 192; ++k) acc = fmaf(h3[(size_t)m * 192 + k], w4[k], acc);
    float pred = acc + b4[0];
    float ef = (float)exp(-(double)pred);
    probs[m] = 1.0f / (1.0f + ef);
}

__global__ void k_select(const float* __restrict__ probs, float* __restrict__ pout, int* __restrict__ sf) {
    int b = blockIdx.x, t = threadIdx.x;
    __shared__ float pr[256];
    __shared__ double ft[256];
    __shared__ int cxy[2];
    pr[t] = probs[b * 256 + t];
    __syncthreads();
    int X = t >> 4, Y = t & 15;
    double s = 0.0;
    for (int dx = -1; dx <= 1; ++dx)
        for (int dy = -1; dy <= 1; ++dy) {
            int xx = X + dx, yy = Y + dy;
            if (xx >= 0 && xx < 16 && yy >= 0 && yy < 16) s += (double)pr[xx * 16 + yy];
        }
    ft[t] = s;
    __syncthreads();
    if (t == 0) {
        double best = ft[0]; int bi = 0;
        for (int i = 1; i < 256; ++i) if (ft[i] > best) { best = ft[i]; bi = i; }
        cxy[0] = bi >> 4; cxy[1] = bi & 15;
    }
    __syncthreads();
    int cx = cxy[0], cy = cxy[1];
    int ax = X - cx; if (ax < 0) ax = -ax;
    int ay = Y - cy; if (ay < 0) ay = -ay;
    bool m7  = (ax <= 3) && (ay <= 3);
    bool m11 = (ax <= 5) && (ay <= 5);
    int fg = (pr[t] > 0.5f) ? 1 : 0;
    sf[b * 256 + t] = m7 ? fg : 0;
    pout[b * 256 + t] = m11 ? INFINITY : pr[t];
}

__global__ void k_sort(const float* __restrict__ pout, const int* __restrict__ sf, const int* __restrict__ gis,
                       float* __restrict__ keep_out, float* __restrict__ rem_out,
                       int* __restrict__ topk, int* __restrict__ keybg) {
    int b = blockIdx.x, t = threadIdx.x;
    __shared__ float p[256];
    __shared__ int ord[256];
    p[t] = pout[b * 256 + t];
    __syncthreads();
    float pi = p[t];
    int rank = 0;
    for (int j = 0; j < 256; ++j) {
        float pj = p[j];
        rank += (pj > pi) || (pj == pi && j < t);
    }
    ord[rank] = t;
    __syncthreads();
    int idx = ord[t];
    int g = gis[b * 256 + idx];
    if (t < NKEEP) {
        keep_out[b * NKEEP + t] = (float)g;
        topk[b * NKEEP + t] = idx;
        keybg[b * NNEW + LTN + t] = (sf[b * 256 + idx] == 0) ? 1 : 0;
    } else {
        rem_out[b * NREM + (t - NKEEP)] = (float)g;
    }
    if (t < LTN) keybg[b * NNEW + t] = 0;
}

__global__ void k_xnew(const float* __restrict__ x, const int* __restrict__ topk, float* __restrict__ xn) {
    int row = blockIdx.x;
    int b = row / NNEW, r = row - b * NNEW;
    int src = (r < LTN) ? r : (LTN + topk[b * NKEEP + (r - LTN)]);
    const float* s = x + (size_t)(b * NTOK + src) * CCH;
    float* d = xn + (size_t)row * CCH;
    for (int c = threadIdx.x; c < CCH; c += 256) d[c] = s[c];
}

// ================= transformer: bf16 MFMA path =================

__global__ void k_ln_bf(const float* __restrict__ in, const float* __restrict__ w, const float* __restrict__ b,
                        u16* __restrict__ out) {
    int row = blockIdx.x, t = threadIdx.x;
    __shared__ float s1[256], s2[256];
    const float* p = in + (size_t)row * CCH;
    float v[3]; float a0 = 0.f, a1 = 0.f;
#pragma unroll
    for (int i = 0; i < 3; ++i) { v[i] = p[t + 256 * i]; a0 += v[i]; a1 += v[i] * v[i]; }
    s1[t] = a0; s2[t] = a1;
    __syncthreads();
    for (int off = 128; off > 0; off >>= 1) {
        if (t < off) { s1[t] += s1[t + off]; s2[t] += s2[t + off]; }
        __syncthreads();
    }
    float mu = s1[0] * (1.0f / CCH);
    float var = s2[0] * (1.0f / CCH) - mu * mu;
    float rstd = rsqrtf(var + 1e-5f);
#pragma unroll
    for (int i = 0; i < 3; ++i) {
        int c = t + 256 * i;
        out[(size_t)row * CCH + c] = f2bf((v[i] - mu) * rstd * w[c] + b[c]);
    }
}

__global__ void k_wT(const float* __restrict__ W, u16* __restrict__ Wt, int K, int N) {
    __shared__ float tile[32][33];
    int k0 = blockIdx.x * 32, n0 = blockIdx.y * 32;
    int tx = threadIdx.x, ty = threadIdx.y;
    for (int i = ty; i < 32; i += 8) tile[i][tx] = W[(size_t)(k0 + i) * N + n0 + tx];
    __syncthreads();
    for (int i = ty; i < 32; i += 8) Wt[(size_t)(n0 + i) * K + k0 + tx] = f2bf(tile[tx][i]);
}

// MFMA GEMM: A[M][K] bf16, Bt[N][K] bf16. 128x128 tile, BK=32, 4 waves.
template<int MODE>
__global__ __launch_bounds__(256) void gemm_bf16(const u16* __restrict__ A, const u16* __restrict__ Bt,
                                                 const float* __restrict__ bias, const float* __restrict__ res,
                                                 float* __restrict__ outf, u16* __restrict__ outb,
                                                 u16* __restrict__ vT, int N, int K) {
    __shared__ u16 sm[2][2][4096];
    int t = threadIdx.x, lane = t & 63, wid = t >> 6;
    int bm = blockIdx.y * 128, bn = blockIdx.x * 128;
    const u16* pA[2]; const u16* pB[2];
#pragma unroll
    for (int i = 0; i < 2; ++i) {
        int L = wid * 128 + i * 64 + lane;
        int line = L >> 3, sp = L & 7, sl = sp ^ (line & 7);
        int r = (line << 1) | (sl >> 2), k0 = (sl & 3) << 3;
        pA[i] = A + (size_t)(bm + r) * K + k0;
        pB[i] = Bt + (size_t)(bn + r) * K + k0;
    }
    int wr = wid >> 1, wc = wid & 1;
    int l15 = lane & 15, l4 = lane >> 4;
    int rA = wr * 64 + l15, rB = wc * 64 + l15;
    int offA = (rA >> 1) * 128 + (((((rA & 1) << 2) | l4)) ^ ((rA >> 1) & 7)) * 16;
    int offB = (rB >> 1) * 128 + (((((rB & 1) << 2) | l4)) ^ ((rB >> 1) & 7)) * 16;
    f4v zero = {0.f, 0.f, 0.f, 0.f};
    f4v acc[4][4];
#pragma unroll
    for (int i = 0; i < 4; ++i)
#pragma unroll
        for (int j = 0; j < 4; ++j) acc[i][j] = zero;

#define STAGE_G(buf, kt) { \
    u16* da = &sm[buf][0][wid * 1024]; u16* db = &sm[buf][1][wid * 1024]; \
    gl_lds16(pA[0] + (kt) * 32, da); \
    gl_lds16(pA[1] + (kt) * 32, da + 512); \
    gl_lds16(pB[0] + (kt) * 32, db); \
    gl_lds16(pB[1] + (kt) * 32, db + 512); \
}
    int nk = K >> 5;
    STAGE_G(0, 0);
    __syncthreads();
    for (int kt = 0; kt < nk; ++kt) {
        int cur = kt & 1;
        if (kt + 1 < nk) STAGE_G(cur ^ 1, kt + 1);
        const char* bA = (const char*)&sm[cur][0][0];
        const char* bBp = (const char*)&sm[cur][1][0];
        s8v a[4], b[4];
#pragma unroll
        for (int i = 0; i < 4; ++i) {
            a[i] = *(const s8v*)(bA + offA + i * 1024);
            b[i] = *(const s8v*)(bBp + offB + i * 1024);
        }
#pragma unroll
        for (int mf = 0; mf < 4; ++mf)
#pragma unroll
            for (int nf = 0; nf < 4; ++nf)
                acc[mf][nf] = __builtin_amdgcn_mfma_f32_16x16x32_bf16(a[mf], b[nf], acc[mf][nf], 0, 0, 0);
        __syncthreads();
    }
#undef STAGE_G
#pragma unroll
    for (int mf = 0; mf < 4; ++mf)
#pragma unroll
        for (int nf = 0; nf < 4; ++nf)
#pragma unroll
            for (int j = 0; j < 4; ++j) {
                int row = bm + wr * 64 + mf * 16 + l4 * 4 + j;
                int col = bn + wc * 64 + nf * 16 + l15;
                float v = acc[mf][nf][j];
                if (MODE == 0) {
                    if (col < 1536) {
                        if (col < 768) v *= 0.125f;
                        outb[(size_t)row * 1536 + col] = f2bf(v);
                    } else {
                        int c2 = col - 1536, hh = c2 >> 6, dd = c2 & 63;
                        int bb = row / NNEW, tok = row - bb * NNEW;
                        vT[(((size_t)bb * NHH + hh) * 64 + dd) * 312 + tok] = f2bf(v);
                    }
                } else if (MODE == 1) {
                    outf[(size_t)row * N + col] = v + bias[col] + res[(size_t)row * N + col];
                } else {
                    float g = v + bias[col];
                    g = 0.5f * g * (1.0f + erff(g * 0.70710678f));
                    outb[(size_t)row * N + col] = f2bf(g);
                }
            }
}

// MFMA attention
__global__ __launch_bounds__(256) void k_attn2(const u16* __restrict__ qkvQK, const u16* __restrict__ vT,
                                               const int* __restrict__ keybg,
                                               float* __restrict__ attn_out, u16* __restrict__ ctx) {
    __shared__ __align__(16) char smem[98560];
    u16* Qs = (u16*)smem;                       // [64][72]
    u16* Ks = (u16*)(smem + 9216);              // [320][72]  (later Vt [64][312])
    u16* Ss = (u16*)(smem + 55296);             // [64][328]  (later OT f32 [64][65])
    int* kb = (int*)(smem + 97280);             // [320]
    float* OT = (float*)Ss;
    u16* Vts = Ks;

    int bh = blockIdx.y; int b = bh / NHH, h = bh % NHH;
    int q0 = blockIdx.x * 64;
    int nq = NNEW - q0; if (nq > 64) nq = 64;
    int t = threadIdx.x, lane = t & 63, wid = t >> 6;
    int l15 = lane & 15, l4 = lane >> 4;
    s8v z = {0, 0, 0, 0, 0, 0, 0, 0};

    {
        int r = t >> 2, c = (t & 3) * 16;
        u16* dst = Qs + r * 72 + c;
        if (r < nq) {
            const u16* src = qkvQK + (size_t)(b * NNEW + q0 + r) * 1536 + h * 64 + c;
            *(s8v*)dst = *(const s8v*)src;
            *(s8v*)(dst + 8) = *(const s8v*)(src + 8);
        } else { *(s8v*)dst = z; *(s8v*)(dst + 8) = z; }
    }
    for (int it = 0; it < 5; ++it) {
        int r = it * 64 + (t >> 2), c = (t & 3) * 16;
        u16* dst = Ks + r * 72 + c;
        if (r < NNEW) {
            const u16* src = qkvQK + (size_t)(b * NNEW + r) * 1536 + 768 + h * 64 + c;
            *(s8v*)dst = *(const s8v*)src;
            *(s8v*)(dst + 8) = *(const s8v*)(src + 8);
        } else { *(s8v*)dst = z; *(s8v*)(dst + 8) = z; }
    }
    for (int i = t; i < 320; i += 256) kb[i] = (i < NNEW) ? keybg[b * NNEW + i] : 1;
    __syncthreads();

    f4v zero = {0.f, 0.f, 0.f, 0.f};
    f4v acc[4][5];
#pragma unroll
    for (int i = 0; i < 4; ++i)
#pragma unroll
        for (int j = 0; j < 5; ++j) acc[i][j] = zero;
#pragma unroll
    for (int ks = 0; ks < 2; ++ks) {
        s8v a[4], bf[5];
#pragma unroll
        for (int mf = 0; mf < 4; ++mf) a[mf] = *(const s8v*)(Qs + (mf * 16 + l15) * 72 + ks * 32 + l4 * 8);
#pragma unroll
        for (int nf = 0; nf < 5; ++nf) bf[nf] = *(const s8v*)(Ks + (wid * 80 + nf * 16 + l15) * 72 + ks * 32 + l4 * 8);
#pragma unroll
        for (int mf = 0; mf < 4; ++mf)
#pragma unroll
            for (int nf = 0; nf < 5; ++nf)
                acc[mf][nf] = __builtin_amdgcn_mfma_f32_16x16x32_bf16(a[mf], bf[nf], acc[mf][nf], 0, 0, 0);
    }
#pragma unroll
    for (int nf = 0; nf < 5; ++nf) {
        int n = wid * 80 + nf * 16 + l15;
        int msk = kb[n];
#pragma unroll
        for (int mf = 0; mf < 4; ++mf)
#pragma unroll
            for (int j = 0; j < 4; ++j) {
                int q = mf * 16 + l4 * 4 + j;
                float v = msk ? -1e9f : acc[mf][nf][j];
                Ss[q * 328 + n] = f2bf(v);
            }
    }
    __syncthreads();

    {
        int d = t >> 2;
        for (int c = (t & 3); c < 39; c += 4) {
            const u16* src = vT + ((size_t)bh * 64 + d) * 312 + c * 8;
            *(s8v*)(Vts + d * 312 + c * 8) = *(const s8v*)src;
        }
    }
    {
        int q = t >> 2, j4 = t & 3;
        u16* row = Ss + q * 328 + j4 * 80;
        float mx = -3e38f;
#pragma unroll
        for (int i = 0; i < 10; ++i) {
            s8v vv = *(const s8v*)(row + i * 8);
#pragma unroll
            for (int e = 0; e < 8; ++e) mx = fmaxf(mx, bf2f((u16)vv[e]));
        }
        mx = fmaxf(mx, __shfl_xor(mx, 1));
        mx = fmaxf(mx, __shfl_xor(mx, 2));
        float sum = 0.f;
#pragma unroll
        for (int i = 0; i < 10; ++i) {
            s8v vv = *(const s8v*)(row + i * 8);
            s8v ov;
#pragma unroll
            for (int e = 0; e < 8; ++e) {
                float ex = expf(bf2f((u16)vv[e]) - mx);
                sum += ex;
                ov[e] = (short)f2bf(ex);
            }
            *(s8v*)(row + i * 8) = ov;
        }
        sum += __shfl_xor(sum, 1);
        sum += __shfl_xor(sum, 2);
        float inv = 1.0f / sum;
#pragma unroll
        for (int i = 0; i < 10; ++i) {
            s8v vv = *(const s8v*)(row + i * 8);
            s8v ov;
            float pf[8];
#pragma unroll
            for (int e = 0; e < 8; ++e) {
                float p = bf2f((u16)vv[e]) * inv;
                pf[e] = p;
                ov[e] = (short)f2bf(p);
            }
            *(s8v*)(row + i * 8) = ov;
            if (q < nq) {
                int n0 = j4 * 80 + i * 8;
                float* dst = attn_out + ((size_t)bh * NNEW + q0 + q) * NNEW + n0;
#pragma unroll
                for (int e = 0; e < 8; ++e) if (n0 + e < NNEW) dst[e] = pf[e];
            }
        }
    }
    __syncthreads();

    f4v o[4];
#pragma unroll
    for (int i = 0; i < 4; ++i) o[i] = zero;
    int dblk = wid * 16;
#pragma unroll
    for (int ks = 0; ks < 10; ++ks) {
        s8v av = *(const s8v*)(Vts + (dblk + l15) * 312 + ks * 32 + l4 * 8);
#pragma unroll
        for (int nf = 0; nf < 4; ++nf) {
            s8v pv = *(const s8v*)(Ss + (nf * 16 + l15) * 328 + ks * 32 + l4 * 8);
            o[nf] = __builtin_amdgcn_mfma_f32_16x16x32_bf16(av, pv, o[nf], 0, 0, 0);
        }
    }
    __syncthreads();
#pragma unroll
    for (int nf = 0; nf < 4; ++nf)
#pragma unroll
        for (int j = 0; j < 4; ++j)
            OT[(dblk + l4 * 4 + j) * 65 + nf * 16 + l15] = o[nf][j];
    __syncthreads();
    {
        int q = t >> 2, c = t & 3;
        if (q < nq) {
            u16 buf[16];
#pragma unroll
            for (int i = 0; i < 16; ++i) buf[i] = f2bf(OT[(c * 16 + i) * 65 + q]);
            u16* dst = ctx + (size_t)(b * NNEW + q0 + q) * CCH + h * 64 + c * 16;
            *(s8v*)dst = *(const s8v*)&buf[0];
            *(s8v*)(dst + 8) = *(const s8v*)&buf[8];
        }
    }
}

// ================= launch =================
extern "C" void kernel_launch(void* const* d_in, const int* in_sizes, int n_in,
                              void* d_out, int out_size, void* d_ws, size_t ws_size,
                              hipStream_t stream) {
    const float* x     = (const float*)d_in[0];
    const int*   gis   = (const int*)d_in[2];
    const float* mask  = (const float*)d_in[3];
    const float* ln1w  = (const float*)d_in[4];
    const float* ln1b  = (const float*)d_in[5];
    const float* qkvw  = (const float*)d_in[6];
    const float* projw = (const float*)d_in[7];
    const float* projb = (const float*)d_in[8];
    const float* ln2w  = (const float*)d_in[9];
    const float* ln2b  = (const float*)d_in[10];
    const float* fc1w  = (const float*)d_in[11];
    const float* fc1b  = (const float*)d_in[12];
    const float* fc2w  = (const float*)d_in[13];
    const float* fc2b  = (const float*)d_in[14];
    const float* d1w   = (const float*)d_in[15];
    const float* d1b   = (const float*)d_in[16];
    const float* d2w   = (const float*)d_in[17];
    const float* d2b   = (const float*)d_in[18];
    const float* d3w   = (const float*)d_in[19];
    const float* d3b   = (const float*)d_in[20];
    const float* d4w   = (const float*)d_in[21];
    const float* d4b   = (const float*)d_in[22];

    float* out_x    = (float*)d_out;
    float* out_keep = out_x + 7569408;
    float* out_rem  = out_keep + 5760;
    float* out_attn = out_rem + 2432;

    char* ws = (char*)d_ws;
    u16* hn_bf  = (u16*)(ws);
    u16* qkvQK  = (u16*)(ws + 15138816);
    u16* vTb    = (u16*)(ws + 45416448);
    u16* fc1_bf = (u16*)(ws);
    u16* ctx_bf = (u16*)(ws + 60751872);
    u16* qkvwT  = (u16*)(ws + 75890688);
    u16* projwT = (u16*)(ws + 79429632);
    u16* fc1wT  = (u16*)(ws + 80609280);
    u16* fc2wT  = (u16*)(ws + 85327872);
    char* misc  = ws + 90046464;
    float* rep0  = (float*)(misc + 0 * 262144);
    float* rep1  = (float*)(misc + 1 * 262144);
    float* probs = (float*)(misc + 2 * 262144);
    float* pout  = (float*)(misc + 3 * 262144);
    int*   sf    = (int*)(misc + 4 * 262144);
    int*   topk  = (int*)(misc + 5 * 262144);
    int*   keybg = (int*)(misc + 6 * 262144);
    size_t required = 90046464ull + 7ull * 262144ull;
    if (ws_size < required) {
        k_fail<<<1, 1, 0, stream>>>((float*)d_out, (float)(ws_size / 1048576.0));
        return;
    }

    float* h1 = (float*)out_attn;
    float* h2 = h1 + 8192 * 768;
    float* h3 = h2 + 8192 * 384;

    k_wT<<<dim3(24, 72), dim3(32, 8), 0, stream>>>(qkvw, qkvwT, 768, 2304);
    k_wT<<<dim3(24, 24), dim3(32, 8), 0, stream>>>(projw, projwT, 768, 768);
    k_wT<<<dim3(24, 96), dim3(32, 8), 0, stream>>>(fc1w, fc1wT, 768, 3072);
    k_wT<<<dim3(96, 24), dim3(32, 8), 0, stream>>>(fc2w, fc2wT, 3072, 768);
    hipMemsetAsync(vTb, 0, 15335424, stream);

    k_reps<<<BB, 256, 0, stream>>>(x, mask, rep0, rep1);
    gemm_head_reg<1><<<1536, 256, 0, stream>>>(x, rep0, rep1, d1w, d1b, h1, 768, 2304, 12);
    gemm_head_reg<0><<<768, 256, 0, stream>>>(h1, nullptr, nullptr, d2w, d2b, h2, 384, 768, 6);
    gemm_head_reg<0><<<384, 256, 0, stream>>>(h2, nullptr, nullptr, d3w, d3b, h3, 192, 384, 3);
    k_d4<<<MS / 256, 256, 0, stream>>>(h3, d4w, d4b, probs);
    k_select<<<BB, 256, 0, stream>>>(probs, pout, sf);
    k_sort<<<BB, 256, 0, stream>>>(pout, sf, gis, out_keep, out_rem, topk, keybg);
    k_xnew<<<MN, 256, 0, stream>>>(x, topk, out_x);

    k_ln_bf<<<MN, 256, 0, stream>>>(out_x, ln1w, ln1b, hn_bf);
    gemm_bf16<0><<<dim3(18, 77), 256, 0, stream>>>(hn_bf, qkvwT, nullptr, nullptr, nullptr, qkvQK, vTb, 2304, 768);
    k_attn2<<<dim3(5, 384), 256, 0, stream>>>(qkvQK, vTb, keybg, out_attn, ctx_bf);
    gemm_bf16<1><<<dim3(6, 77), 256, 0, stream>>>(ctx_bf, projwT, projb, out_x, out_x, nullptr, nullptr, 768, 768);
    k_ln_bf<<<MN, 256, 0, stream>>>(out_x, ln2w, ln2b, ctx_bf);
    gemm_bf16<2><<<dim3(24, 77), 256, 0, stream>>>(ctx_bf, fc1wT, fc1b, nullptr, nullptr, fc1_bf, nullptr, 3072, 768);
    gemm_bf16<1><<<dim3(6, 77), 256, 0, stream>>>(fc1_bf, fc2wT, fc2b, out_x, out_x, nullptr, nullptr, 768, 3072);
}

// Round 9
// 1092.572 us; speedup vs baseline: 2.0166x; 2.0166x over previous
//
#include <hip/hip_runtime.h>
#include <hip/hip_bf16.h>
#include <math.h>

#define BB 32
#define LSN 256
#define LTN 128
#define CCH 768
#define NHH 12
#define NTOK 384
#define NKEEP 180
#define NREM 76
#define NNEW 308
#define MS 8192    /* B*LS */
#define MN 9856    /* B*NNEW */

typedef unsigned short u16;
typedef __attribute__((ext_vector_type(8))) short s8v;
typedef __attribute__((ext_vector_type(4))) float f4v;

__device__ __forceinline__ u16 f2bf(float x) {
    union { __hip_bfloat16 b; u16 u; } c; c.b = __float2bfloat16(x); return c.u;
}
__device__ __forceinline__ float bf2f(u16 u) {
    return __uint_as_float(((unsigned)u) << 16);
}
__device__ __forceinline__ void gl_lds16(const u16* g, u16* l) {
    __builtin_amdgcn_global_load_lds((const __attribute__((address_space(1))) unsigned*)g,
                                     (__attribute__((address_space(3))) unsigned*)l, 16, 0, 0);
}

__global__ void k_fail(float* o, float v) { o[0] = v; }

// ================= exact head (same FP ops/order as round 3 — bit-exact sort keys) =================
__global__ void k_reps(const float* __restrict__ x, const float* __restrict__ mask,
                       float* __restrict__ rep0, float* __restrict__ rep1) {
    int b = blockIdx.x, t = threadIdx.x;
    for (int c = t; c < CCH; c += 256) {
        float m0 = -INFINITY, m1 = -INFINITY;
        for (int i = 0; i < 64; ++i) {
            float v0 = x[(size_t)(b * NTOK + i) * CCH + c] * mask[b * 64 + i];
            float v1 = x[(size_t)(b * NTOK + 64 + i) * CCH + c] * mask[BB * 64 + b * 64 + i];
            m0 = fmaxf(m0, v0); m1 = fmaxf(m1, v1);
        }
        rep0[b * CCH + c] = m0; rep1[b * CCH + c] = m1;
    }
}

__device__ __forceinline__ float gelu_np(float v) {
    float t = v / 1.4142135623730951f;
    float ef = (float)erf((double)t);
    return 0.5f * v * (1.0f + ef);
}

// d1: 128x64 tile, 8x4 acc/thread, TK=32. 1.5 B LDS per FMA (vs 2.0 at 4x4).
// k-chain per output strictly ascending, one accumulator => bit-exact.
template<int ROWMAP>
__global__ __launch_bounds__(256) void gemm_exact84(const float* __restrict__ A,
                                                    const float* __restrict__ rep0, const float* __restrict__ rep1,
                                                    const float* __restrict__ W, const float* __restrict__ bias,
                                                    float* __restrict__ out, int N, int K) {
    __shared__ float As[32 * 128];  // [k][row]
    __shared__ float Bs[32 * 64];   // [k][col] flat
    int t = threadIdx.x;
    int tx = t & 15, ty = t >> 4;
    int bm = blockIdx.y * 128, bn = blockIdx.x * 64;
    int b = bm >> 8;
    float acc[8][4] = {};

    // A staging: thread covers row = t>>1, k block base aks = (t&1)*16, 4 float4s
    int arow = t >> 1;
    int aks = (t & 1) * 16;
    size_t aoff;
    if (ROWMAP) aoff = (size_t)(b * NTOK + LTN + ((bm + arow) & 255)) * CCH;
    else        aoff = (size_t)(bm + arow) * K;

    // B staging: same proven scheme as 64x64 template (flat contiguous)
    int bkr = t >> 4, bc = (t & 15) * 4;

#define LOADA(kg) (ROWMAP ? (((kg) < CCH) ? *(const float4*)&A[aoff + (kg)] \
                    : (((kg) < 2*CCH) ? *(const float4*)&rep0[b*CCH + (kg) - CCH] \
                                      : *(const float4*)&rep1[b*CCH + (kg) - 2*CCH])) \
                   : *(const float4*)&A[aoff + (kg)])

    int nt = K >> 5;
    float4 ra[4];
#pragma unroll
    for (int i = 0; i < 4; ++i) ra[i] = LOADA(aks + 4 * i);
    float4 rb0 = *(const float4*)&W[(size_t)bkr * N + bn + bc];
    float4 rb1 = *(const float4*)&W[(size_t)(16 + bkr) * N + bn + bc];

    for (int tile = 0; tile < nt; ++tile) {
        __syncthreads();
#pragma unroll
        for (int i = 0; i < 4; ++i) {
            As[(aks + 4 * i + 0) * 128 + arow] = ra[i].x;
            As[(aks + 4 * i + 1) * 128 + arow] = ra[i].y;
            As[(aks + 4 * i + 2) * 128 + arow] = ra[i].z;
            As[(aks + 4 * i + 3) * 128 + arow] = ra[i].w;
        }
        *(float4*)&Bs[t * 4] = rb0;
        *(float4*)&Bs[1024 + t * 4] = rb1;
        if (tile + 1 < nt) {
            int k0 = (tile + 1) << 5;
#pragma unroll
            for (int i = 0; i < 4; ++i) ra[i] = LOADA(k0 + aks + 4 * i);
            rb0 = *(const float4*)&W[(size_t)(k0 + bkr) * N + bn + bc];
            rb1 = *(const float4*)&W[(size_t)(k0 + 16 + bkr) * N + bn + bc];
        }
        __syncthreads();
#pragma unroll 8
        for (int k = 0; k < 32; ++k) {
            float a[8], bv[4];
            *(float4*)&a[0] = *(const float4*)&As[k * 128 + ty * 8];
            *(float4*)&a[4] = *(const float4*)&As[k * 128 + ty * 8 + 4];
            *(float4*)&bv[0] = *(const float4*)&Bs[k * 64 + tx * 4];
#pragma unroll
            for (int i = 0; i < 8; ++i)
#pragma unroll
                for (int j = 0; j < 4; ++j) acc[i][j] = fmaf(a[i], bv[j], acc[i][j]);
        }
    }
#undef LOADA
#pragma unroll
    for (int i = 0; i < 8; ++i) {
        int m = bm + ty * 8 + i;
        float4 o;
        o.x = gelu_np(acc[i][0] + bias[bn + tx * 4 + 0]);
        o.y = gelu_np(acc[i][1] + bias[bn + tx * 4 + 1]);
        o.z = gelu_np(acc[i][2] + bias[bn + tx * 4 + 2]);
        o.w = gelu_np(acc[i][3] + bias[bn + tx * 4 + 3]);
        *(float4*)&out[(size_t)m * N + bn + tx * 4] = o;
    }
}

// 64x64 tile, 4x4 acc (round-7 proven) — used for d2/d3 (keeps grid >= 2 blocks/CU)
template<int ROWMAP>
__global__ __launch_bounds__(256) void gemm_exact(const float* __restrict__ A,
                                                  const float* __restrict__ rep0, const float* __restrict__ rep1,
                                                  const float* __restrict__ W, const float* __restrict__ bias,
                                                  float* __restrict__ out, int N, int K) {
    __shared__ float As[32 * 64];
    __shared__ float Bs[32 * 64];
    int t = threadIdx.x;
    int tx = t & 15, ty = t >> 4;
    int bm = blockIdx.y * 64, bn = blockIdx.x * 64;
    int b = bm >> 8;
    float acc[4][4] = {};

    int arow = t >> 2;
    int ak = (t & 3) * 4;
    int asw = arow ^ ((ak & 4) << 2);
    size_t aoff;
    if (ROWMAP) aoff = (size_t)(b * NTOK + LTN + ((bm + arow) & 255)) * CCH;
    else        aoff = (size_t)(bm + arow) * K;

    int bkr = t >> 4, bc = (t & 15) * 4;

#define LOADA(kg) (ROWMAP ? (((kg) < CCH) ? *(const float4*)&A[aoff + (kg)] \
                    : (((kg) < 2*CCH) ? *(const float4*)&rep0[b*CCH + (kg) - CCH] \
                                      : *(const float4*)&rep1[b*CCH + (kg) - 2*CCH])) \
                   : *(const float4*)&A[aoff + (kg)])

    int nt = K >> 5;
    float4 ra0 = LOADA(ak), ra1 = LOADA(16 + ak);
    float4 rb0 = *(const float4*)&W[(size_t)bkr * N + bn + bc];
    float4 rb1 = *(const float4*)&W[(size_t)(16 + bkr) * N + bn + bc];

    for (int tile = 0; tile < nt; ++tile) {
        __syncthreads();
        As[(ak + 0) * 64 + asw] = ra0.x; As[(ak + 1) * 64 + asw] = ra0.y;
        As[(ak + 2) * 64 + asw] = ra0.z; As[(ak + 3) * 64 + asw] = ra0.w;
        As[(16 + ak + 0) * 64 + asw] = ra1.x; As[(16 + ak + 1) * 64 + asw] = ra1.y;
        As[(16 + ak + 2) * 64 + asw] = ra1.z; As[(16 + ak + 3) * 64 + asw] = ra1.w;
        *(float4*)&Bs[t * 4] = rb0;
        *(float4*)&Bs[1024 + t * 4] = rb1;
        if (tile + 1 < nt) {
            int k0 = (tile + 1) << 5;
            ra0 = LOADA(k0 + ak); ra1 = LOADA(k0 + 16 + ak);
            rb0 = *(const float4*)&W[(size_t)(k0 + bkr) * N + bn + bc];
            rb1 = *(const float4*)&W[(size_t)(k0 + 16 + bkr) * N + bn + bc];
        }
        __syncthreads();
#pragma unroll
        for (int k = 0; k < 32; ++k) {
            float a[4], bv[4];
            *(float4*)&a[0]  = *(const float4*)&As[k * 64 + ((ty * 4) ^ ((k & 4) << 2))];
            *(float4*)&bv[0] = *(const float4*)&Bs[k * 64 + tx * 4];
#pragma unroll
            for (int i = 0; i < 4; ++i)
#pragma unroll
                for (int j = 0; j < 4; ++j) acc[i][j] = fmaf(a[i], bv[j], acc[i][j]);
        }
    }
#undef LOADA
#pragma unroll
    for (int i = 0; i < 4; ++i) {
        int m = bm + ty * 4 + i;
        float4 o;
        o.x = gelu_np(acc[i][0] + bias[bn + tx * 4 + 0]);
        o.y = gelu_np(acc[i][1] + bias[bn + tx * 4 + 1]);
        o.z = gelu_np(acc[i][2] + bias[bn + tx * 4 + 2]);
        o.w = gelu_np(acc[i][3] + bias[bn + tx * 4 + 3]);
        *(float4*)&out[(size_t)m * N + bn + tx * 4] = o;
    }
}

__global__ void k_d4(const float* __restrict__ h3, const float* __restrict__ w4,
                     const float* __restrict__ b4, float* __restrict__ probs) {
    int m = blockIdx.x * 256 + threadIdx.x;
    if (m >= MS) return;
    float acc = 0.f;
    for (int k = 0; k < 192; ++k) acc = fmaf(h3[(size_t)m * 192 + k], w4[k], acc);
    float pred = acc + b4[0];
    float ef = (float)exp(-(double)pred);
    probs[m] = 1.0f / (1.0f + ef);
}

__global__ void k_select(const float* __restrict__ probs, float* __restrict__ pout, int* __restrict__ sf) {
    int b = blockIdx.x, t = threadIdx.x;
    __shared__ float pr[256];
    __shared__ double ft[256];
    __shared__ int cxy[2];
    pr[t] = probs[b * 256 + t];
    __syncthreads();
    int X = t >> 4, Y = t & 15;
    double s = 0.0;
    for (int dx = -1; dx <= 1; ++dx)
        for (int dy = -1; dy <= 1; ++dy) {
            int xx = X + dx, yy = Y + dy;
            if (xx >= 0 && xx < 16 && yy >= 0 && yy < 16) s += (double)pr[xx * 16 + yy];
        }
    ft[t] = s;
    __syncthreads();
    if (t == 0) {
        double best = ft[0]; int bi = 0;
        for (int i = 1; i < 256; ++i) if (ft[i] > best) { best = ft[i]; bi = i; }
        cxy[0] = bi >> 4; cxy[1] = bi & 15;
    }
    __syncthreads();
    int cx = cxy[0], cy = cxy[1];
    int ax = X - cx; if (ax < 0) ax = -ax;
    int ay = Y - cy; if (ay < 0) ay = -ay;
    bool m7  = (ax <= 3) && (ay <= 3);
    bool m11 = (ax <= 5) && (ay <= 5);
    int fg = (pr[t] > 0.5f) ? 1 : 0;
    sf[b * 256 + t] = m7 ? fg : 0;
    pout[b * 256 + t] = m11 ? INFINITY : pr[t];
}

__global__ void k_sort(const float* __restrict__ pout, const int* __restrict__ sf, const int* __restrict__ gis,
                       float* __restrict__ keep_out, float* __restrict__ rem_out,
                       int* __restrict__ topk, int* __restrict__ keybg) {
    int b = blockIdx.x, t = threadIdx.x;
    __shared__ float p[256];
    __shared__ int ord[256];
    p[t] = pout[b * 256 + t];
    __syncthreads();
    float pi = p[t];
    int rank = 0;
    for (int j = 0; j < 256; ++j) {
        float pj = p[j];
        rank += (pj > pi) || (pj == pi && j < t);
    }
    ord[rank] = t;
    __syncthreads();
    int idx = ord[t];
    int g = gis[b * 256 + idx];
    if (t < NKEEP) {
        keep_out[b * NKEEP + t] = (float)g;
        topk[b * NKEEP + t] = idx;
        keybg[b * NNEW + LTN + t] = (sf[b * 256 + idx] == 0) ? 1 : 0;
    } else {
        rem_out[b * NREM + (t - NKEEP)] = (float)g;
    }
    if (t < LTN) keybg[b * NNEW + t] = 0;
}

__global__ void k_xnew(const float* __restrict__ x, const int* __restrict__ topk, float* __restrict__ xn) {
    int row = blockIdx.x;
    int b = row / NNEW, r = row - b * NNEW;
    int src = (r < LTN) ? r : (LTN + topk[b * NKEEP + (r - LTN)]);
    const float* s = x + (size_t)(b * NTOK + src) * CCH;
    float* d = xn + (size_t)row * CCH;
    for (int c = threadIdx.x; c < CCH; c += 256) d[c] = s[c];
}

// ================= transformer: bf16 MFMA path =================

__global__ void k_ln_bf(const float* __restrict__ in, const float* __restrict__ w, const float* __restrict__ b,
                        u16* __restrict__ out) {
    int row = blockIdx.x, t = threadIdx.x;
    __shared__ float s1[256], s2[256];
    const float* p = in + (size_t)row * CCH;
    float v[3]; float a0 = 0.f, a1 = 0.f;
#pragma unroll
    for (int i = 0; i < 3; ++i) { v[i] = p[t + 256 * i]; a0 += v[i]; a1 += v[i] * v[i]; }
    s1[t] = a0; s2[t] = a1;
    __syncthreads();
    for (int off = 128; off > 0; off >>= 1) {
        if (t < off) { s1[t] += s1[t + off]; s2[t] += s2[t + off]; }
        __syncthreads();
    }
    float mu = s1[0] * (1.0f / CCH);
    float var = s2[0] * (1.0f / CCH) - mu * mu;
    float rstd = rsqrtf(var + 1e-5f);
#pragma unroll
    for (int i = 0; i < 3; ++i) {
        int c = t + 256 * i;
        out[(size_t)row * CCH + c] = f2bf((v[i] - mu) * rstd * w[c] + b[c]);
    }
}

__global__ void k_wT(const float* __restrict__ W, u16* __restrict__ Wt, int K, int N) {
    __shared__ float tile[32][33];
    int k0 = blockIdx.x * 32, n0 = blockIdx.y * 32;
    int tx = threadIdx.x, ty = threadIdx.y;
    for (int i = ty; i < 32; i += 8) tile[i][tx] = W[(size_t)(k0 + i) * N + n0 + tx];
    __syncthreads();
    for (int i = ty; i < 32; i += 8) Wt[(size_t)(n0 + i) * K + k0 + tx] = f2bf(tile[tx][i]);
}

// MFMA GEMM: A[M][K] bf16, Bt[N][K] bf16. 128x128 tile, BK=32, 4 waves.
template<int MODE>
__global__ __launch_bounds__(256) void gemm_bf16(const u16* __restrict__ A, const u16* __restrict__ Bt,
                                                 const float* __restrict__ bias, const float* __restrict__ res,
                                                 float* __restrict__ outf, u16* __restrict__ outb,
                                                 u16* __restrict__ vT, int N, int K) {
    __shared__ u16 sm[2][2][4096];
    int t = threadIdx.x, lane = t & 63, wid = t >> 6;
    int bm = blockIdx.y * 128, bn = blockIdx.x * 128;
    const u16* pA[2]; const u16* pB[2];
#pragma unroll
    for (int i = 0; i < 2; ++i) {
        int L = wid * 128 + i * 64 + lane;
        int line = L >> 3, sp = L & 7, sl = sp ^ (line & 7);
        int r = (line << 1) | (sl >> 2), k0 = (sl & 3) << 3;
        pA[i] = A + (size_t)(bm + r) * K + k0;
        pB[i] = Bt + (size_t)(bn + r) * K + k0;
    }
    int wr = wid >> 1, wc = wid & 1;
    int l15 = lane & 15, l4 = lane >> 4;
    int rA = wr * 64 + l15, rB = wc * 64 + l15;
    int offA = (rA >> 1) * 128 + (((((rA & 1) << 2) | l4)) ^ ((rA >> 1) & 7)) * 16;
    int offB = (rB >> 1) * 128 + (((((rB & 1) << 2) | l4)) ^ ((rB >> 1) & 7)) * 16;
    f4v zero = {0.f, 0.f, 0.f, 0.f};
    f4v acc[4][4];
#pragma unroll
    for (int i = 0; i < 4; ++i)
#pragma unroll
        for (int j = 0; j < 4; ++j) acc[i][j] = zero;

#define STAGE_G(buf, kt) { \
    u16* da = &sm[buf][0][wid * 1024]; u16* db = &sm[buf][1][wid * 1024]; \
    gl_lds16(pA[0] + (kt) * 32, da); \
    gl_lds16(pA[1] + (kt) * 32, da + 512); \
    gl_lds16(pB[0] + (kt) * 32, db); \
    gl_lds16(pB[1] + (kt) * 32, db + 512); \
}
    int nk = K >> 5;
    STAGE_G(0, 0);
    __syncthreads();
    for (int kt = 0; kt < nk; ++kt) {
        int cur = kt & 1;
        if (kt + 1 < nk) STAGE_G(cur ^ 1, kt + 1);
        const char* bA = (const char*)&sm[cur][0][0];
        const char* bBp = (const char*)&sm[cur][1][0];
        s8v a[4], b[4];
#pragma unroll
        for (int i = 0; i < 4; ++i) {
            a[i] = *(const s8v*)(bA + offA + i * 1024);
            b[i] = *(const s8v*)(bBp + offB + i * 1024);
        }
#pragma unroll
        for (int mf = 0; mf < 4; ++mf)
#pragma unroll
            for (int nf = 0; nf < 4; ++nf)
                acc[mf][nf] = __builtin_amdgcn_mfma_f32_16x16x32_bf16(a[mf], b[nf], acc[mf][nf], 0, 0, 0);
        __syncthreads();
    }
#undef STAGE_G
#pragma unroll
    for (int mf = 0; mf < 4; ++mf)
#pragma unroll
        for (int nf = 0; nf < 4; ++nf)
#pragma unroll
            for (int j = 0; j < 4; ++j) {
                int row = bm + wr * 64 + mf * 16 + l4 * 4 + j;
                int col = bn + wc * 64 + nf * 16 + l15;
                float v = acc[mf][nf][j];
                if (MODE == 0) {
                    if (col < 1536) {
                        if (col < 768) v *= 0.125f;
                        outb[(size_t)row * 1536 + col] = f2bf(v);
                    } else {
                        int c2 = col - 1536, hh = c2 >> 6, dd = c2 & 63;
                        int bb = row / NNEW, tok = row - bb * NNEW;
                        vT[(((size_t)bb * NHH + hh) * 64 + dd) * 312 + tok] = f2bf(v);
                    }
                } else if (MODE == 1) {
                    outf[(size_t)row * N + col] = v + bias[col] + res[(size_t)row * N + col];
                } else {
                    float g = v + bias[col];
                    g = 0.5f * g * (1.0f + erff(g * 0.70710678f));
                    outb[(size_t)row * N + col] = f2bf(g);
                }
            }
}

// MFMA attention
__global__ __launch_bounds__(256) void k_attn2(const u16* __restrict__ qkvQK, const u16* __restrict__ vT,
                                               const int* __restrict__ keybg,
                                               float* __restrict__ attn_out, u16* __restrict__ ctx) {
    __shared__ __align__(16) char smem[98560];
    u16* Qs = (u16*)smem;                       // [64][72]
    u16* Ks = (u16*)(smem + 9216);              // [320][72]  (later Vt [64][312])
    u16* Ss = (u16*)(smem + 55296);             // [64][328]  (later OT f32 [64][65])
    int* kb = (int*)(smem + 97280);             // [320]
    float* OT = (float*)Ss;
    u16* Vts = Ks;

    int bh = blockIdx.y; int b = bh / NHH, h = bh % NHH;
    int q0 = blockIdx.x * 64;
    int nq = NNEW - q0; if (nq > 64) nq = 64;
    int t = threadIdx.x, lane = t & 63, wid = t >> 6;
    int l15 = lane & 15, l4 = lane >> 4;
    s8v z = {0, 0, 0, 0, 0, 0, 0, 0};

    {
        int r = t >> 2, c = (t & 3) * 16;
        u16* dst = Qs + r * 72 + c;
        if (r < nq) {
            const u16* src = qkvQK + (size_t)(b * NNEW + q0 + r) * 1536 + h * 64 + c;
            *(s8v*)dst = *(const s8v*)src;
            *(s8v*)(dst + 8) = *(const s8v*)(src + 8);
        } else { *(s8v*)dst = z; *(s8v*)(dst + 8) = z; }
    }
    for (int it = 0; it < 5; ++it) {
        int r = it * 64 + (t >> 2), c = (t & 3) * 16;
        u16* dst = Ks + r * 72 + c;
        if (r < NNEW) {
            const u16* src = qkvQK + (size_t)(b * NNEW + r) * 1536 + 768 + h * 64 + c;
            *(s8v*)dst = *(const s8v*)src;
            *(s8v*)(dst + 8) = *(const s8v*)(src + 8);
        } else { *(s8v*)dst = z; *(s8v*)(dst + 8) = z; }
    }
    for (int i = t; i < 320; i += 256) kb[i] = (i < NNEW) ? keybg[b * NNEW + i] : 1;
    __syncthreads();

    f4v zero = {0.f, 0.f, 0.f, 0.f};
    f4v acc[4][5];
#pragma unroll
    for (int i = 0; i < 4; ++i)
#pragma unroll
        for (int j = 0; j < 5; ++j) acc[i][j] = zero;
#pragma unroll
    for (int ks = 0; ks < 2; ++ks) {
        s8v a[4], bf[5];
#pragma unroll
        for (int mf = 0; mf < 4; ++mf) a[mf] = *(const s8v*)(Qs + (mf * 16 + l15) * 72 + ks * 32 + l4 * 8);
#pragma unroll
        for (int nf = 0; nf < 5; ++nf) bf[nf] = *(const s8v*)(Ks + (wid * 80 + nf * 16 + l15) * 72 + ks * 32 + l4 * 8);
#pragma unroll
        for (int mf = 0; mf < 4; ++mf)
#pragma unroll
            for (int nf = 0; nf < 5; ++nf)
                acc[mf][nf] = __builtin_amdgcn_mfma_f32_16x16x32_bf16(a[mf], bf[nf], acc[mf][nf], 0, 0, 0);
    }
#pragma unroll
    for (int nf = 0; nf < 5; ++nf) {
        int n = wid * 80 + nf * 16 + l15;
        int msk = kb[n];
#pragma unroll
        for (int mf = 0; mf < 4; ++mf)
#pragma unroll
            for (int j = 0; j < 4; ++j) {
                int q = mf * 16 + l4 * 4 + j;
                float v = msk ? -1e9f : acc[mf][nf][j];
                Ss[q * 328 + n] = f2bf(v);
            }
    }
    __syncthreads();

    {
        int d = t >> 2;
        for (int c = (t & 3); c < 39; c += 4) {
            const u16* src = vT + ((size_t)bh * 64 + d) * 312 + c * 8;
            *(s8v*)(Vts + d * 312 + c * 8) = *(const s8v*)src;
        }
    }
    {
        int q = t >> 2, j4 = t & 3;
        u16* row = Ss + q * 328 + j4 * 80;
        float mx = -3e38f;
#pragma unroll
        for (int i = 0; i < 10; ++i) {
            s8v vv = *(const s8v*)(row + i * 8);
#pragma unroll
            for (int e = 0; e < 8; ++e) mx = fmaxf(mx, bf2f((u16)vv[e]));
        }
        mx = fmaxf(mx, __shfl_xor(mx, 1));
        mx = fmaxf(mx, __shfl_xor(mx, 2));
        float sum = 0.f;
#pragma unroll
        for (int i = 0; i < 10; ++i) {
            s8v vv = *(const s8v*)(row + i * 8);
            s8v ov;
#pragma unroll
            for (int e = 0; e < 8; ++e) {
                float ex = expf(bf2f((u16)vv[e]) - mx);
                sum += ex;
                ov[e] = (short)f2bf(ex);
            }
            *(s8v*)(row + i * 8) = ov;
        }
        sum += __shfl_xor(sum, 1);
        sum += __shfl_xor(sum, 2);
        float inv = 1.0f / sum;
#pragma unroll
        for (int i = 0; i < 10; ++i) {
            s8v vv = *(const s8v*)(row + i * 8);
            s8v ov;
            float pf[8];
#pragma unroll
            for (int e = 0; e < 8; ++e) {
                float p = bf2f((u16)vv[e]) * inv;
                pf[e] = p;
                ov[e] = (short)f2bf(p);
            }
            *(s8v*)(row + i * 8) = ov;
            if (q < nq) {
                int n0 = j4 * 80 + i * 8;
                float* dst = attn_out + ((size_t)bh * NNEW + q0 + q) * NNEW + n0;
#pragma unroll
                for (int e = 0; e < 8; ++e) if (n0 + e < NNEW) dst[e] = pf[e];
            }
        }
    }
    __syncthreads();

    f4v o[4];
#pragma unroll
    for (int i = 0; i < 4; ++i) o[i] = zero;
    int dblk = wid * 16;
#pragma unroll
    for (int ks = 0; ks < 10; ++ks) {
        s8v av = *(const s8v*)(Vts + (dblk + l15) * 312 + ks * 32 + l4 * 8);
#pragma unroll
        for (int nf = 0; nf < 4; ++nf) {
            s8v pv = *(const s8v*)(Ss + (nf * 16 + l15) * 328 + ks * 32 + l4 * 8);
            o[nf] = __builtin_amdgcn_mfma_f32_16x16x32_bf16(av, pv, o[nf], 0, 0, 0);
        }
    }
    __syncthreads();
#pragma unroll
    for (int nf = 0; nf < 4; ++nf)
#pragma unroll
        for (int j = 0; j < 4; ++j)
            OT[(dblk + l4 * 4 + j) * 65 + nf * 16 + l15] = o[nf][j];
    __syncthreads();
    {
        int q = t >> 2, c = t & 3;
        if (q < nq) {
            u16 buf[16];
#pragma unroll
            for (int i = 0; i < 16; ++i) buf[i] = f2bf(OT[(c * 16 + i) * 65 + q]);
            u16* dst = ctx + (size_t)(b * NNEW + q0 + q) * CCH + h * 64 + c * 16;
            *(s8v*)dst = *(const s8v*)&buf[0];
            *(s8v*)(dst + 8) = *(const s8v*)&buf[8];
        }
    }
}

// ================= launch =================
extern "C" void kernel_launch(void* const* d_in, const int* in_sizes, int n_in,
                              void* d_out, int out_size, void* d_ws, size_t ws_size,
                              hipStream_t stream) {
    const float* x     = (const float*)d_in[0];
    const int*   gis   = (const int*)d_in[2];
    const float* mask  = (const float*)d_in[3];
    const float* ln1w  = (const float*)d_in[4];
    const float* ln1b  = (const float*)d_in[5];
    const float* qkvw  = (const float*)d_in[6];
    const float* projw = (const float*)d_in[7];
    const float* projb = (const float*)d_in[8];
    const float* ln2w  = (const float*)d_in[9];
    const float* ln2b  = (const float*)d_in[10];
    const float* fc1w  = (const float*)d_in[11];
    const float* fc1b  = (const float*)d_in[12];
    const float* fc2w  = (const float*)d_in[13];
    const float* fc2b  = (const float*)d_in[14];
    const float* d1w   = (const float*)d_in[15];
    const float* d1b   = (const float*)d_in[16];
    const float* d2w   = (const float*)d_in[17];
    const float* d2b   = (const float*)d_in[18];
    const float* d3w   = (const float*)d_in[19];
    const float* d3b   = (const float*)d_in[20];
    const float* d4w   = (const float*)d_in[21];
    const float* d4b   = (const float*)d_in[22];

    float* out_x    = (float*)d_out;
    float* out_keep = out_x + 7569408;
    float* out_rem  = out_keep + 5760;
    float* out_attn = out_rem + 2432;

    char* ws = (char*)d_ws;
    u16* hn_bf  = (u16*)(ws);
    u16* qkvQK  = (u16*)(ws + 15138816);
    u16* vTb    = (u16*)(ws + 45416448);
    u16* fc1_bf = (u16*)(ws);
    u16* ctx_bf = (u16*)(ws + 60751872);
    u16* qkvwT  = (u16*)(ws + 75890688);
    u16* projwT = (u16*)(ws + 79429632);
    u16* fc1wT  = (u16*)(ws + 80609280);
    u16* fc2wT  = (u16*)(ws + 85327872);
    char* misc  = ws + 90046464;
    float* rep0  = (float*)(misc + 0 * 262144);
    float* rep1  = (float*)(misc + 1 * 262144);
    float* probs = (float*)(misc + 2 * 262144);
    float* pout  = (float*)(misc + 3 * 262144);
    int*   sf    = (int*)(misc + 4 * 262144);
    int*   topk  = (int*)(misc + 5 * 262144);
    int*   keybg = (int*)(misc + 6 * 262144);
    size_t required = 90046464ull + 7ull * 262144ull;
    if (ws_size < required) {
        k_fail<<<1, 1, 0, stream>>>((float*)d_out, (float)(ws_size / 1048576.0));
        return;
    }

    float* h1 = (float*)out_attn;
    float* h2 = h1 + 8192 * 768;
    float* h3 = h2 + 8192 * 384;

    k_wT<<<dim3(24, 72), dim3(32, 8), 0, stream>>>(qkvw, qkvwT, 768, 2304);
    k_wT<<<dim3(24, 24), dim3(32, 8), 0, stream>>>(projw, projwT, 768, 768);
    k_wT<<<dim3(24, 96), dim3(32, 8), 0, stream>>>(fc1w, fc1wT, 768, 3072);
    k_wT<<<dim3(96, 24), dim3(32, 8), 0, stream>>>(fc2w, fc2wT, 3072, 768);
    hipMemsetAsync(vTb, 0, 15335424, stream);

    k_reps<<<BB, 256, 0, stream>>>(x, mask, rep0, rep1);
    gemm_exact84<1><<<dim3(12, 64), 256, 0, stream>>>(x, rep0, rep1, d1w, d1b, h1, 768, 2304);
    gemm_exact<0><<<dim3(6, 128), 256, 0, stream>>>(h1, nullptr, nullptr, d2w, d2b, h2, 384, 768);
    gemm_exact<0><<<dim3(3, 128), 256, 0, stream>>>(h2, nullptr, nullptr, d3w, d3b, h3, 192, 384);
    k_d4<<<MS / 256, 256, 0, stream>>>(h3, d4w, d4b, probs);
    k_select<<<BB, 256, 0, stream>>>(probs, pout, sf);
    k_sort<<<BB, 256, 0, stream>>>(pout, sf, gis, out_keep, out_rem, topk, keybg);
    k_xnew<<<MN, 256, 0, stream>>>(x, topk, out_x);

    k_ln_bf<<<MN, 256, 0, stream>>>(out_x, ln1w, ln1b, hn_bf);
    gemm_bf16<0><<<dim3(18, 77), 256, 0, stream>>>(hn_bf, qkvwT, nullptr, nullptr, nullptr, qkvQK, vTb, 2304, 768);
    k_attn2<<<dim3(5, 384), 256, 0, stream>>>(qkvQK, vTb, keybg, out_attn, ctx_bf);
    gemm_bf16<1><<<dim3(6, 77), 256, 0, stream>>>(ctx_bf, projwT, projb, out_x, out_x, nullptr, nullptr, 768, 768);
    k_ln_bf<<<MN, 256, 0, stream>>>(out_x, ln2w, ln2b, ctx_bf);
    gemm_bf16<2><<<dim3(24, 77), 256, 0, stream>>>(ctx_bf, fc1wT, fc1b, nullptr, nullptr, fc1_bf, nullptr, 3072, 768);
    gemm_bf16<1><<<dim3(6, 77), 256, 0, stream>>>(fc1_bf, fc2wT, fc2b, out_x, out_x, nullptr, nullptr, 768, 3072);
}

// Round 10
// 1039.496 us; speedup vs baseline: 2.1196x; 1.0511x over previous
//
#include <hip/hip_runtime.h>
#include <hip/hip_bf16.h>
#include <math.h>

#define BB 32
#define LSN 256
#define LTN 128
#define CCH 768
#define NHH 12
#define NTOK 384
#define NKEEP 180
#define NREM 76
#define NNEW 308
#define MS 8192    /* B*LS */
#define MN 9856    /* B*NNEW */

typedef unsigned short u16;
typedef __attribute__((ext_vector_type(8))) short s8v;
typedef __attribute__((ext_vector_type(4))) float f4v;

__device__ __forceinline__ u16 f2bf(float x) {
    union { __hip_bfloat16 b; u16 u; } c; c.b = __float2bfloat16(x); return c.u;
}
__device__ __forceinline__ float bf2f(u16 u) {
    return __uint_as_float(((unsigned)u) << 16);
}
__device__ __forceinline__ void gl_lds16(const u16* g, u16* l) {
    __builtin_amdgcn_global_load_lds((const __attribute__((address_space(1))) unsigned*)g,
                                     (__attribute__((address_space(3))) unsigned*)l, 16, 0, 0);
}
// bijective XCD-chunked swizzle (m204): consecutive logical tiles land on one XCD
__device__ __forceinline__ int xcd_swz(int lin, int nwg) {
    int q = nwg >> 3, r = nwg & 7;
    int xcd = lin & 7, idx = lin >> 3;
    return (xcd < r ? xcd * (q + 1) : r * (q + 1) + (xcd - r) * q) + idx;
}

__global__ void k_fail(float* o, float v) { o[0] = v; }

// ================= exact head (same FP ops/order as round 3 — bit-exact sort keys) =================
__global__ void k_reps(const float* __restrict__ x, const float* __restrict__ mask,
                       float* __restrict__ rep0, float* __restrict__ rep1) {
    int b = blockIdx.x, t = threadIdx.x;
    for (int c = t; c < CCH; c += 256) {
        float m0 = -INFINITY, m1 = -INFINITY;
        for (int i = 0; i < 64; ++i) {
            float v0 = x[(size_t)(b * NTOK + i) * CCH + c] * mask[b * 64 + i];
            float v1 = x[(size_t)(b * NTOK + 64 + i) * CCH + c] * mask[BB * 64 + b * 64 + i];
            m0 = fmaxf(m0, v0); m1 = fmaxf(m1, v1);
        }
        rep0[b * CCH + c] = m0; rep1[b * CCH + c] = m1;
    }
}

__device__ __forceinline__ float gelu_np(float v) {
    float t = v / 1.4142135623730951f;
    float ef = (float)erf((double)t);
    return 0.5f * v * (1.0f + ef);
}

// Exact-head GEMM: 64x64 tile, TK=32, 4x4 acc (round-7 proven, 93% of its LDS roofline).
template<int ROWMAP>
__global__ __launch_bounds__(256) void gemm_exact(const float* __restrict__ A,
                                                  const float* __restrict__ rep0, const float* __restrict__ rep1,
                                                  const float* __restrict__ W, const float* __restrict__ bias,
                                                  float* __restrict__ out, int N, int K) {
    __shared__ float As[32 * 64];   // [k][row^swz], swz = (k&4)<<2
    __shared__ float Bs[32 * 64];   // [k][col] flat
    int t = threadIdx.x;
    int tx = t & 15, ty = t >> 4;
    int bm = blockIdx.y * 64, bn = blockIdx.x * 64;
    int b = bm >> 8;
    float acc[4][4] = {};

    int arow = t >> 2;
    int ak = (t & 3) * 4;
    int asw = arow ^ ((ak & 4) << 2);
    size_t aoff;
    if (ROWMAP) aoff = (size_t)(b * NTOK + LTN + ((bm + arow) & 255)) * CCH;
    else        aoff = (size_t)(bm + arow) * K;

    int bkr = t >> 4, bc = (t & 15) * 4;

#define LOADA(kg) (ROWMAP ? (((kg) < CCH) ? *(const float4*)&A[aoff + (kg)] \
                    : (((kg) < 2*CCH) ? *(const float4*)&rep0[b*CCH + (kg) - CCH] \
                                      : *(const float4*)&rep1[b*CCH + (kg) - 2*CCH])) \
                   : *(const float4*)&A[aoff + (kg)])

    int nt = K >> 5;
    float4 ra0 = LOADA(ak), ra1 = LOADA(16 + ak);
    float4 rb0 = *(const float4*)&W[(size_t)bkr * N + bn + bc];
    float4 rb1 = *(const float4*)&W[(size_t)(16 + bkr) * N + bn + bc];

    for (int tile = 0; tile < nt; ++tile) {
        __syncthreads();
        As[(ak + 0) * 64 + asw] = ra0.x; As[(ak + 1) * 64 + asw] = ra0.y;
        As[(ak + 2) * 64 + asw] = ra0.z; As[(ak + 3) * 64 + asw] = ra0.w;
        As[(16 + ak + 0) * 64 + asw] = ra1.x; As[(16 + ak + 1) * 64 + asw] = ra1.y;
        As[(16 + ak + 2) * 64 + asw] = ra1.z; As[(16 + ak + 3) * 64 + asw] = ra1.w;
        *(float4*)&Bs[t * 4] = rb0;
        *(float4*)&Bs[1024 + t * 4] = rb1;
        if (tile + 1 < nt) {
            int k0 = (tile + 1) << 5;
            ra0 = LOADA(k0 + ak); ra1 = LOADA(k0 + 16 + ak);
            rb0 = *(const float4*)&W[(size_t)(k0 + bkr) * N + bn + bc];
            rb1 = *(const float4*)&W[(size_t)(k0 + 16 + bkr) * N + bn + bc];
        }
        __syncthreads();
#pragma unroll
        for (int k = 0; k < 32; ++k) {
            float a[4], bv[4];
            *(float4*)&a[0]  = *(const float4*)&As[k * 64 + ((ty * 4) ^ ((k & 4) << 2))];
            *(float4*)&bv[0] = *(const float4*)&Bs[k * 64 + tx * 4];
#pragma unroll
            for (int i = 0; i < 4; ++i)
#pragma unroll
                for (int j = 0; j < 4; ++j) acc[i][j] = fmaf(a[i], bv[j], acc[i][j]);
        }
    }
#undef LOADA
#pragma unroll
    for (int i = 0; i < 4; ++i) {
        int m = bm + ty * 4 + i;
        float4 o;
        o.x = gelu_np(acc[i][0] + bias[bn + tx * 4 + 0]);
        o.y = gelu_np(acc[i][1] + bias[bn + tx * 4 + 1]);
        o.z = gelu_np(acc[i][2] + bias[bn + tx * 4 + 2]);
        o.w = gelu_np(acc[i][3] + bias[bn + tx * 4 + 3]);
        *(float4*)&out[(size_t)m * N + bn + tx * 4] = o;
    }
}

__global__ void k_d4(const float* __restrict__ h3, const float* __restrict__ w4,
                     const float* __restrict__ b4, float* __restrict__ probs) {
    int m = blockIdx.x * 256 + threadIdx.x;
    if (m >= MS) return;
    float acc = 0.f;
    for (int k = 0; k < 192; ++k) acc = fmaf(h3[(size_t)m * 192 + k], w4[k], acc);
    float pred = acc + b4[0];
    float ef = (float)exp(-(double)pred);
    probs[m] = 1.0f / (1.0f + ef);
}

// fused select (box filter/argmax/masks) + stable sort + outputs
__global__ void k_selsort(const float* __restrict__ probs, const int* __restrict__ gis,
                          float* __restrict__ keep_out, float* __restrict__ rem_out,
                          int* __restrict__ topk, int* __restrict__ keybg) {
    int b = blockIdx.x, t = threadIdx.x;
    __shared__ float pr[256];
    __shared__ double ft[256];
    __shared__ int cxy[2];
    __shared__ float pout[256];
    __shared__ int sf[256];
    __shared__ int ord[256];
    pr[t] = probs[b * 256 + t];
    __syncthreads();
    int X = t >> 4, Y = t & 15;
    double s = 0.0;
    for (int dx = -1; dx <= 1; ++dx)
        for (int dy = -1; dy <= 1; ++dy) {
            int xx = X + dx, yy = Y + dy;
            if (xx >= 0 && xx < 16 && yy >= 0 && yy < 16) s += (double)pr[xx * 16 + yy];
        }
    ft[t] = s;
    __syncthreads();
    if (t == 0) {
        double best = ft[0]; int bi = 0;
        for (int i = 1; i < 256; ++i) if (ft[i] > best) { best = ft[i]; bi = i; }
        cxy[0] = bi >> 4; cxy[1] = bi & 15;
    }
    __syncthreads();
    int cx = cxy[0], cy = cxy[1];
    int ax = X - cx; if (ax < 0) ax = -ax;
    int ay = Y - cy; if (ay < 0) ay = -ay;
    bool m7  = (ax <= 3) && (ay <= 3);
    bool m11 = (ax <= 5) && (ay <= 5);
    int fg = (pr[t] > 0.5f) ? 1 : 0;
    sf[t] = m7 ? fg : 0;
    pout[t] = m11 ? INFINITY : pr[t];
    __syncthreads();
    float pi = pout[t];
    int rank = 0;
    for (int j = 0; j < 256; ++j) {
        float pj = pout[j];
        rank += (pj > pi) || (pj == pi && j < t);
    }
    ord[rank] = t;
    __syncthreads();
    int idx = ord[t];
    int g = gis[b * 256 + idx];
    if (t < NKEEP) {
        keep_out[b * NKEEP + t] = (float)g;
        topk[b * NKEEP + t] = idx;
        keybg[b * NNEW + LTN + t] = (sf[idx] == 0) ? 1 : 0;
    } else {
        rem_out[b * NREM + (t - NKEEP)] = (float)g;
    }
    if (t < LTN) keybg[b * NNEW + t] = 0;
}

// fused gather + write out_x + LN1 -> bf16
__global__ void k_xnew_ln(const float* __restrict__ x, const int* __restrict__ topk,
                          const float* __restrict__ w, const float* __restrict__ b,
                          float* __restrict__ out_x, u16* __restrict__ hn) {
    int row = blockIdx.x, t = threadIdx.x;
    int bb = row / NNEW, r = row - bb * NNEW;
    int src = (r < LTN) ? r : (LTN + topk[bb * NKEEP + (r - LTN)]);
    const float* p = x + (size_t)(bb * NTOK + src) * CCH;
    __shared__ float s1[256], s2[256];
    float v[3]; float a0 = 0.f, a1 = 0.f;
#pragma unroll
    for (int i = 0; i < 3; ++i) { v[i] = p[t + 256 * i]; a0 += v[i]; a1 += v[i] * v[i]; }
#pragma unroll
    for (int i = 0; i < 3; ++i) out_x[(size_t)row * CCH + t + 256 * i] = v[i];
    s1[t] = a0; s2[t] = a1;
    __syncthreads();
    for (int off = 128; off > 0; off >>= 1) {
        if (t < off) { s1[t] += s1[t + off]; s2[t] += s2[t + off]; }
        __syncthreads();
    }
    float mu = s1[0] * (1.0f / CCH);
    float var = s2[0] * (1.0f / CCH) - mu * mu;
    float rstd = rsqrtf(var + 1e-5f);
#pragma unroll
    for (int i = 0; i < 3; ++i) {
        int c = t + 256 * i;
        hn[(size_t)row * CCH + c] = f2bf((v[i] - mu) * rstd * w[c] + b[c]);
    }
}

// ================= transformer: bf16 MFMA path =================

__global__ void k_ln_bf(const float* __restrict__ in, const float* __restrict__ w, const float* __restrict__ b,
                        u16* __restrict__ out) {
    int row = blockIdx.x, t = threadIdx.x;
    __shared__ float s1[256], s2[256];
    const float* p = in + (size_t)row * CCH;
    float v[3]; float a0 = 0.f, a1 = 0.f;
#pragma unroll
    for (int i = 0; i < 3; ++i) { v[i] = p[t + 256 * i]; a0 += v[i]; a1 += v[i] * v[i]; }
    s1[t] = a0; s2[t] = a1;
    __syncthreads();
    for (int off = 128; off > 0; off >>= 1) {
        if (t < off) { s1[t] += s1[t + off]; s2[t] += s2[t + off]; }
        __syncthreads();
    }
    float mu = s1[0] * (1.0f / CCH);
    float var = s2[0] * (1.0f / CCH) - mu * mu;
    float rstd = rsqrtf(var + 1e-5f);
#pragma unroll
    for (int i = 0; i < 3; ++i) {
        int c = t + 256 * i;
        out[(size_t)row * CCH + c] = f2bf((v[i] - mu) * rstd * w[c] + b[c]);
    }
}

// fused prep: 4 weight transposes + vT zero-fill, one launch
__global__ void k_prep(const float* __restrict__ qkvw, const float* __restrict__ projw,
                       const float* __restrict__ fc1w, const float* __restrict__ fc2w,
                       u16* __restrict__ qkvwT, u16* __restrict__ projwT,
                       u16* __restrict__ fc1wT, u16* __restrict__ fc2wT,
                       u16* __restrict__ vTb) {
    int id = blockIdx.x;
    int t = threadIdx.x;
    if (id >= 6912) {   // vT zero section: 3744 blocks x 4KB
        size_t off = ((size_t)(id - 6912) * 256 + t) * 8;
        s8v z = {0,0,0,0,0,0,0,0};
        *(s8v*)(vTb + off) = z;
        return;
    }
    const float* W; u16* Wt; int K, N, tile;
    if (id < 1728)      { W = qkvw;  Wt = qkvwT;  K = 768;  N = 2304; tile = id; }
    else if (id < 2304) { W = projw; Wt = projwT; K = 768;  N = 768;  tile = id - 1728; }
    else if (id < 4608) { W = fc1w;  Wt = fc1wT;  K = 768;  N = 3072; tile = id - 2304; }
    else                { W = fc2w;  Wt = fc2wT;  K = 3072; N = 768;  tile = id - 4608; }
    int kt = K >> 5;
    int k0 = (tile % kt) * 32, n0 = (tile / kt) * 32;
    __shared__ float tilebuf[32][33];
    int tx = t & 31, ty = t >> 5;
    for (int i = ty; i < 32; i += 8) tilebuf[i][tx] = W[(size_t)(k0 + i) * N + n0 + tx];
    __syncthreads();
    for (int i = ty; i < 32; i += 8) Wt[(size_t)(n0 + i) * K + k0 + tx] = f2bf(tilebuf[tx][i]);
}

// MFMA GEMM: A[M][K] bf16, Bt[N][K] bf16. 128x128 tile, BK=32, 4 waves. XCD-swizzled grid.
template<int MODE>
__global__ __launch_bounds__(256) void gemm_bf16(const u16* __restrict__ A, const u16* __restrict__ Bt,
                                                 const float* __restrict__ bias, const float* __restrict__ res,
                                                 float* __restrict__ outf, u16* __restrict__ outb,
                                                 u16* __restrict__ vT, int N, int K) {
    __shared__ u16 sm[2][2][4096];
    int t = threadIdx.x, lane = t & 63, wid = t >> 6;
    int nwg = gridDim.x * gridDim.y;
    int lin = blockIdx.y * gridDim.x + blockIdx.x;
    int T = xcd_swz(lin, nwg);
    int bx = T % gridDim.x, by = T / gridDim.x;
    int bm = by * 128, bn = bx * 128;
    const u16* pA[2]; const u16* pB[2];
#pragma unroll
    for (int i = 0; i < 2; ++i) {
        int L = wid * 128 + i * 64 + lane;
        int line = L >> 3, sp = L & 7, sl = sp ^ (line & 7);
        int r = (line << 1) | (sl >> 2), k0 = (sl & 3) << 3;
        pA[i] = A + (size_t)(bm + r) * K + k0;
        pB[i] = Bt + (size_t)(bn + r) * K + k0;
    }
    int wr = wid >> 1, wc = wid & 1;
    int l15 = lane & 15, l4 = lane >> 4;
    int rA = wr * 64 + l15, rB = wc * 64 + l15;
    int offA = (rA >> 1) * 128 + (((((rA & 1) << 2) | l4)) ^ ((rA >> 1) & 7)) * 16;
    int offB = (rB >> 1) * 128 + (((((rB & 1) << 2) | l4)) ^ ((rB >> 1) & 7)) * 16;
    f4v zero = {0.f, 0.f, 0.f, 0.f};
    f4v acc[4][4];
#pragma unroll
    for (int i = 0; i < 4; ++i)
#pragma unroll
        for (int j = 0; j < 4; ++j) acc[i][j] = zero;

#define STAGE_G(buf, kt) { \
    u16* da = &sm[buf][0][wid * 1024]; u16* db = &sm[buf][1][wid * 1024]; \
    gl_lds16(pA[0] + (kt) * 32, da); \
    gl_lds16(pA[1] + (kt) * 32, da + 512); \
    gl_lds16(pB[0] + (kt) * 32, db); \
    gl_lds16(pB[1] + (kt) * 32, db + 512); \
}
    int nk = K >> 5;
    STAGE_G(0, 0);
    __syncthreads();
    for (int kt = 0; kt < nk; ++kt) {
        int cur = kt & 1;
        if (kt + 1 < nk) STAGE_G(cur ^ 1, kt + 1);
        const char* bA = (const char*)&sm[cur][0][0];
        const char* bBp = (const char*)&sm[cur][1][0];
        s8v a[4], b[4];
#pragma unroll
        for (int i = 0; i < 4; ++i) {
            a[i] = *(const s8v*)(bA + offA + i * 1024);
            b[i] = *(const s8v*)(bBp + offB + i * 1024);
        }
#pragma unroll
        for (int mf = 0; mf < 4; ++mf)
#pragma unroll
            for (int nf = 0; nf < 4; ++nf)
                acc[mf][nf] = __builtin_amdgcn_mfma_f32_16x16x32_bf16(a[mf], b[nf], acc[mf][nf], 0, 0, 0);
        __syncthreads();
    }
#undef STAGE_G
#pragma unroll
    for (int mf = 0; mf < 4; ++mf)
#pragma unroll
        for (int nf = 0; nf < 4; ++nf)
#pragma unroll
            for (int j = 0; j < 4; ++j) {
                int row = bm + wr * 64 + mf * 16 + l4 * 4 + j;
                int col = bn + wc * 64 + nf * 16 + l15;
                float v = acc[mf][nf][j];
                if (MODE == 0) {
                    if (col < 1536) {
                        if (col < 768) v *= 0.125f;
                        outb[(size_t)row * 1536 + col] = f2bf(v);
                    } else {
                        int c2 = col - 1536, hh = c2 >> 6, dd = c2 & 63;
                        int bb = row / NNEW, tok = row - bb * NNEW;
                        vT[(((size_t)bb * NHH + hh) * 64 + dd) * 312 + tok] = f2bf(v);
                    }
                } else if (MODE == 1) {
                    outf[(size_t)row * N + col] = v + bias[col] + res[(size_t)row * N + col];
                } else {
                    float g = v + bias[col];
                    g = 0.5f * g * (1.0f + erff(g * 0.70710678f));
                    outb[(size_t)row * N + col] = f2bf(g);
                }
            }
}

// MFMA attention (XCD-swizzled block map)
__global__ __launch_bounds__(256) void k_attn2(const u16* __restrict__ qkvQK, const u16* __restrict__ vT,
                                               const int* __restrict__ keybg,
                                               float* __restrict__ attn_out, u16* __restrict__ ctx) {
    __shared__ __align__(16) char smem[98560];
    u16* Qs = (u16*)smem;                       // [64][72]
    u16* Ks = (u16*)(smem + 9216);              // [320][72]  (later Vt [64][312])
    u16* Ss = (u16*)(smem + 55296);             // [64][328]  (later OT f32 [64][65])
    int* kb = (int*)(smem + 97280);             // [320]
    float* OT = (float*)Ss;
    u16* Vts = Ks;

    int nwg = gridDim.x * gridDim.y;
    int lin = blockIdx.y * gridDim.x + blockIdx.x;
    int T = xcd_swz(lin, nwg);
    int bh = T / 5;
    int q0 = (T - bh * 5) * 64;
    int b = bh / NHH, h = bh % NHH;
    int nq = NNEW - q0; if (nq > 64) nq = 64;
    int t = threadIdx.x, lane = t & 63, wid = t >> 6;
    int l15 = lane & 15, l4 = lane >> 4;
    s8v z = {0, 0, 0, 0, 0, 0, 0, 0};

    {
        int r = t >> 2, c = (t & 3) * 16;
        u16* dst = Qs + r * 72 + c;
        if (r < nq) {
            const u16* src = qkvQK + (size_t)(b * NNEW + q0 + r) * 1536 + h * 64 + c;
            *(s8v*)dst = *(const s8v*)src;
            *(s8v*)(dst + 8) = *(const s8v*)(src + 8);
        } else { *(s8v*)dst = z; *(s8v*)(dst + 8) = z; }
    }
    for (int it = 0; it < 5; ++it) {
        int r = it * 64 + (t >> 2), c = (t & 3) * 16;
        u16* dst = Ks + r * 72 + c;
        if (r < NNEW) {
            const u16* src = qkvQK + (size_t)(b * NNEW + r) * 1536 + 768 + h * 64 + c;
            *(s8v*)dst = *(const s8v*)src;
            *(s8v*)(dst + 8) = *(const s8v*)(src + 8);
        } else { *(s8v*)dst = z; *(s8v*)(dst + 8) = z; }
    }
    for (int i = t; i < 320; i += 256) kb[i] = (i < NNEW) ? keybg[b * NNEW + i] : 1;
    __syncthreads();

    f4v zero = {0.f, 0.f, 0.f, 0.f};
    f4v acc[4][5];
#pragma unroll
    for (int i = 0; i < 4; ++i)
#pragma unroll
        for (int j = 0; j < 5; ++j) acc[i][j] = zero;
#pragma unroll
    for (int ks = 0; ks < 2; ++ks) {
        s8v a[4], bf[5];
#pragma unroll
        for (int mf = 0; mf < 4; ++mf) a[mf] = *(const s8v*)(Qs + (mf * 16 + l15) * 72 + ks * 32 + l4 * 8);
#pragma unroll
        for (int nf = 0; nf < 5; ++nf) bf[nf] = *(const s8v*)(Ks + (wid * 80 + nf * 16 + l15) * 72 + ks * 32 + l4 * 8);
#pragma unroll
        for (int mf = 0; mf < 4; ++mf)
#pragma unroll
            for (int nf = 0; nf < 5; ++nf)
                acc[mf][nf] = __builtin_amdgcn_mfma_f32_16x16x32_bf16(a[mf], bf[nf], acc[mf][nf], 0, 0, 0);
    }
#pragma unroll
    for (int nf = 0; nf < 5; ++nf) {
        int n = wid * 80 + nf * 16 + l15;
        int msk = kb[n];
#pragma unroll
        for (int mf = 0; mf < 4; ++mf)
#pragma unroll
            for (int j = 0; j < 4; ++j) {
                int q = mf * 16 + l4 * 4 + j;
                float v = msk ? -1e9f : acc[mf][nf][j];
                Ss[q * 328 + n] = f2bf(v);
            }
    }
    __syncthreads();

    {
        int d = t >> 2;
        for (int c = (t & 3); c < 39; c += 4) {
            const u16* src = vT + ((size_t)bh * 64 + d) * 312 + c * 8;
            *(s8v*)(Vts + d * 312 + c * 8) = *(const s8v*)src;
        }
    }
    {
        int q = t >> 2, j4 = t & 3;
        u16* row = Ss + q * 328 + j4 * 80;
        float mx = -3e38f;
#pragma unroll
        for (int i = 0; i < 10; ++i) {
            s8v vv = *(const s8v*)(row + i * 8);
#pragma unroll
            for (int e = 0; e < 8; ++e) mx = fmaxf(mx, bf2f((u16)vv[e]));
        }
        mx = fmaxf(mx, __shfl_xor(mx, 1));
        mx = fmaxf(mx, __shfl_xor(mx, 2));
        float sum = 0.f;
#pragma unroll
        for (int i = 0; i < 10; ++i) {
            s8v vv = *(const s8v*)(row + i * 8);
            s8v ov;
#pragma unroll
            for (int e = 0; e < 8; ++e) {
                float ex = expf(bf2f((u16)vv[e]) - mx);
                sum += ex;
                ov[e] = (short)f2bf(ex);
            }
            *(s8v*)(row + i * 8) = ov;
        }
        sum += __shfl_xor(sum, 1);
        sum += __shfl_xor(sum, 2);
        float inv = 1.0f / sum;
#pragma unroll
        for (int i = 0; i < 10; ++i) {
            s8v vv = *(const s8v*)(row + i * 8);
            s8v ov;
            float pf[8];
#pragma unroll
            for (int e = 0; e < 8; ++e) {
                float p = bf2f((u16)vv[e]) * inv;
                pf[e] = p;
                ov[e] = (short)f2bf(p);
            }
            *(s8v*)(row + i * 8) = ov;
            if (q < nq) {
                int n0 = j4 * 80 + i * 8;
                float* dst = attn_out + ((size_t)bh * NNEW + q0 + q) * NNEW + n0;
#pragma unroll
                for (int e = 0; e < 8; ++e) if (n0 + e < NNEW) dst[e] = pf[e];
            }
        }
    }
    __syncthreads();

    f4v o[4];
#pragma unroll
    for (int i = 0; i < 4; ++i) o[i] = zero;
    int dblk = wid * 16;
#pragma unroll
    for (int ks = 0; ks < 10; ++ks) {
        s8v av = *(const s8v*)(Vts + (dblk + l15) * 312 + ks * 32 + l4 * 8);
#pragma unroll
        for (int nf = 0; nf < 4; ++nf) {
            s8v pv = *(const s8v*)(Ss + (nf * 16 + l15) * 328 + ks * 32 + l4 * 8);
            o[nf] = __builtin_amdgcn_mfma_f32_16x16x32_bf16(av, pv, o[nf], 0, 0, 0);
        }
    }
    __syncthreads();
#pragma unroll
    for (int nf = 0; nf < 4; ++nf)
#pragma unroll
        for (int j = 0; j < 4; ++j)
            OT[(dblk + l4 * 4 + j) * 65 + nf * 16 + l15] = o[nf][j];
    __syncthreads();
    {
        int q = t >> 2, c = t & 3;
        if (q < nq) {
            u16 buf[16];
#pragma unroll
            for (int i = 0; i < 16; ++i) buf[i] = f2bf(OT[(c * 16 + i) * 65 + q]);
            u16* dst = ctx + (size_t)(b * NNEW + q0 + q) * CCH + h * 64 + c * 16;
            *(s8v*)dst = *(const s8v*)&buf[0];
            *(s8v*)(dst + 8) = *(const s8v*)&buf[8];
        }
    }
}

// ================= launch =================
extern "C" void kernel_launch(void* const* d_in, const int* in_sizes, int n_in,
                              void* d_out, int out_size, void* d_ws, size_t ws_size,
                              hipStream_t stream) {
    const float* x     = (const float*)d_in[0];
    const int*   gis   = (const int*)d_in[2];
    const float* mask  = (const float*)d_in[3];
    const float* ln1w  = (const float*)d_in[4];
    const float* ln1b  = (const float*)d_in[5];
    const float* qkvw  = (const float*)d_in[6];
    const float* projw = (const float*)d_in[7];
    const float* projb = (const float*)d_in[8];
    const float* ln2w  = (const float*)d_in[9];
    const float* ln2b  = (const float*)d_in[10];
    const float* fc1w  = (const float*)d_in[11];
    const float* fc1b  = (const float*)d_in[12];
    const float* fc2w  = (const float*)d_in[13];
    const float* fc2b  = (const float*)d_in[14];
    const float* d1w   = (const float*)d_in[15];
    const float* d1b   = (const float*)d_in[16];
    const float* d2w   = (const float*)d_in[17];
    const float* d2b   = (const float*)d_in[18];
    const float* d3w   = (const float*)d_in[19];
    const float* d3b   = (const float*)d_in[20];
    const float* d4w   = (const float*)d_in[21];
    const float* d4b   = (const float*)d_in[22];

    float* out_x    = (float*)d_out;
    float* out_keep = out_x + 7569408;
    float* out_rem  = out_keep + 5760;
    float* out_attn = out_rem + 2432;

    char* ws = (char*)d_ws;
    u16* hn_bf  = (u16*)(ws);
    u16* qkvQK  = (u16*)(ws + 15138816);
    u16* vTb    = (u16*)(ws + 45416448);
    u16* fc1_bf = (u16*)(ws);
    u16* ctx_bf = (u16*)(ws + 60751872);
    u16* qkvwT  = (u16*)(ws + 75890688);
    u16* projwT = (u16*)(ws + 79429632);
    u16* fc1wT  = (u16*)(ws + 80609280);
    u16* fc2wT  = (u16*)(ws + 85327872);
    char* misc  = ws + 90046464;
    float* rep0  = (float*)(misc + 0 * 262144);
    float* rep1  = (float*)(misc + 1 * 262144);
    float* probs = (float*)(misc + 2 * 262144);
    int*   topk  = (int*)(misc + 5 * 262144);
    int*   keybg = (int*)(misc + 6 * 262144);
    size_t required = 90046464ull + 7ull * 262144ull;
    if (ws_size < required) {
        k_fail<<<1, 1, 0, stream>>>((float*)d_out, (float)(ws_size / 1048576.0));
        return;
    }

    float* h1 = (float*)out_attn;
    float* h2 = h1 + 8192 * 768;
    float* h3 = h2 + 8192 * 384;

    k_prep<<<10656, 256, 0, stream>>>(qkvw, projw, fc1w, fc2w, qkvwT, projwT, fc1wT, fc2wT, vTb);

    k_reps<<<BB, 256, 0, stream>>>(x, mask, rep0, rep1);
    gemm_exact<1><<<dim3(12, 128), 256, 0, stream>>>(x, rep0, rep1, d1w, d1b, h1, 768, 2304);
    gemm_exact<0><<<dim3(6, 128), 256, 0, stream>>>(h1, nullptr, nullptr, d2w, d2b, h2, 384, 768);
    gemm_exact<0><<<dim3(3, 128), 256, 0, stream>>>(h2, nullptr, nullptr, d3w, d3b, h3, 192, 384);
    k_d4<<<MS / 256, 256, 0, stream>>>(h3, d4w, d4b, probs);
    k_selsort<<<BB, 256, 0, stream>>>(probs, gis, out_keep, out_rem, topk, keybg);
    k_xnew_ln<<<MN, 256, 0, stream>>>(x, topk, ln1w, ln1b, out_x, hn_bf);

    gemm_bf16<0><<<dim3(18, 77), 256, 0, stream>>>(hn_bf, qkvwT, nullptr, nullptr, nullptr, qkvQK, vTb, 2304, 768);
    k_attn2<<<dim3(5, 384), 256, 0, stream>>>(qkvQK, vTb, keybg, out_attn, ctx_bf);
    gemm_bf16<1><<<dim3(6, 77), 256, 0, stream>>>(ctx_bf, projwT, projb, out_x, out_x, nullptr, nullptr, 768, 768);
    k_ln_bf<<<MN, 256, 0, stream>>>(out_x, ln2w, ln2b, ctx_bf);
    gemm_bf16<2><<<dim3(24, 77), 256, 0, stream>>>(ctx_bf, fc1wT, fc1b, nullptr, nullptr, fc1_bf, nullptr, 3072, 768);
    gemm_bf16<1><<<dim3(6, 77), 256, 0, stream>>>(fc1_bf, fc2wT, fc2b, out_x, out_x, nullptr, nullptr, 768, 3072);
}

// Round 11
// 985.446 us; speedup vs baseline: 2.2358x; 1.0548x over previous
//
#include <hip/hip_runtime.h>
#include <hip/hip_bf16.h>
#include <math.h>

#define BB 32
#define LSN 256
#define LTN 128
#define CCH 768
#define NHH 12
#define NTOK 384
#define NKEEP 180
#define NREM 76
#define NNEW 308
#define MS 8192    /* B*LS */
#define MN 9856    /* B*NNEW */

typedef unsigned short u16;
typedef __attribute__((ext_vector_type(8))) short s8v;
typedef __attribute__((ext_vector_type(4))) float f4v;

__device__ __forceinline__ u16 f2bf(float x) {
    union { __hip_bfloat16 b; u16 u; } c; c.b = __float2bfloat16(x); return c.u;
}
__device__ __forceinline__ float bf2f(u16 u) {
    return __uint_as_float(((unsigned)u) << 16);
}
__device__ __forceinline__ void gl_lds16(const u16* g, u16* l) {
    __builtin_amdgcn_global_load_lds((const __attribute__((address_space(1))) unsigned*)g,
                                     (__attribute__((address_space(3))) unsigned*)l, 16, 0, 0);
}
// bijective XCD-chunked swizzle (m204)
__device__ __forceinline__ int xcd_swz(int lin, int nwg) {
    int q = nwg >> 3, r = nwg & 7;
    int xcd = lin & 7, idx = lin >> 3;
    return (xcd < r ? xcd * (q + 1) : r * (q + 1) + (xcd - r) * q) + idx;
}

__global__ void k_fail(float* o, float v) { o[0] = v; }

// ================= exact head (same FP ops/order as round 3 — bit-exact sort keys) =================
// coalesced: iterate rows, threads cover columns. max order-independent => bit-exact.
__global__ void k_reps(const float* __restrict__ x, const float* __restrict__ mask,
                       float* __restrict__ rep0, float* __restrict__ rep1) {
    int b = blockIdx.x, t = threadIdx.x;
    float m0[3] = {-INFINITY, -INFINITY, -INFINITY};
    float m1[3] = {-INFINITY, -INFINITY, -INFINITY};
    for (int i = 0; i < 64; ++i) {
        float mk0 = mask[b * 64 + i];
        float mk1 = mask[BB * 64 + b * 64 + i];
        const float* r0 = x + (size_t)(b * NTOK + i) * CCH;
        const float* r1 = x + (size_t)(b * NTOK + 64 + i) * CCH;
#pragma unroll
        for (int j = 0; j < 3; ++j) {
            m0[j] = fmaxf(m0[j], r0[t + 256 * j] * mk0);
            m1[j] = fmaxf(m1[j], r1[t + 256 * j] * mk1);
        }
    }
#pragma unroll
    for (int j = 0; j < 3; ++j) {
        rep0[b * CCH + t + 256 * j] = m0[j];
        rep1[b * CCH + t + 256 * j] = m1[j];
    }
}

__device__ __forceinline__ float gelu_np(float v) {
    float t = v / 1.4142135623730951f;
    float ef = (float)erf((double)t);
    return 0.5f * v * (1.0f + ef);
}

// Exact-head GEMM: 64x64 tile, TK=32, 4x4 acc (round-7 proven, ~93% of its LDS roofline).
template<int ROWMAP>
__global__ __launch_bounds__(256) void gemm_exact(const float* __restrict__ A,
                                                  const float* __restrict__ rep0, const float* __restrict__ rep1,
                                                  const float* __restrict__ W, const float* __restrict__ bias,
                                                  float* __restrict__ out, int N, int K) {
    __shared__ float As[32 * 64];   // [k][row^swz], swz = (k&4)<<2
    __shared__ float Bs[32 * 64];   // [k][col] flat
    int t = threadIdx.x;
    int tx = t & 15, ty = t >> 4;
    int bm = blockIdx.y * 64, bn = blockIdx.x * 64;
    int b = bm >> 8;
    float acc[4][4] = {};

    int arow = t >> 2;
    int ak = (t & 3) * 4;
    int asw = arow ^ ((ak & 4) << 2);
    size_t aoff;
    if (ROWMAP) aoff = (size_t)(b * NTOK + LTN + ((bm + arow) & 255)) * CCH;
    else        aoff = (size_t)(bm + arow) * K;

    int bkr = t >> 4, bc = (t & 15) * 4;

#define LOADA(kg) (ROWMAP ? (((kg) < CCH) ? *(const float4*)&A[aoff + (kg)] \
                    : (((kg) < 2*CCH) ? *(const float4*)&rep0[b*CCH + (kg) - CCH] \
                                      : *(const float4*)&rep1[b*CCH + (kg) - 2*CCH])) \
                   : *(const float4*)&A[aoff + (kg)])

    int nt = K >> 5;
    float4 ra0 = LOADA(ak), ra1 = LOADA(16 + ak);
    float4 rb0 = *(const float4*)&W[(size_t)bkr * N + bn + bc];
    float4 rb1 = *(const float4*)&W[(size_t)(16 + bkr) * N + bn + bc];

    for (int tile = 0; tile < nt; ++tile) {
        __syncthreads();
        As[(ak + 0) * 64 + asw] = ra0.x; As[(ak + 1) * 64 + asw] = ra0.y;
        As[(ak + 2) * 64 + asw] = ra0.z; As[(ak + 3) * 64 + asw] = ra0.w;
        As[(16 + ak + 0) * 64 + asw] = ra1.x; As[(16 + ak + 1) * 64 + asw] = ra1.y;
        As[(16 + ak + 2) * 64 + asw] = ra1.z; As[(16 + ak + 3) * 64 + asw] = ra1.w;
        *(float4*)&Bs[t * 4] = rb0;
        *(float4*)&Bs[1024 + t * 4] = rb1;
        if (tile + 1 < nt) {
            int k0 = (tile + 1) << 5;
            ra0 = LOADA(k0 + ak); ra1 = LOADA(k0 + 16 + ak);
            rb0 = *(const float4*)&W[(size_t)(k0 + bkr) * N + bn + bc];
            rb1 = *(const float4*)&W[(size_t)(k0 + 16 + bkr) * N + bn + bc];
        }
        __syncthreads();
#pragma unroll
        for (int k = 0; k < 32; ++k) {
            float a[4], bv[4];
            *(float4*)&a[0]  = *(const float4*)&As[k * 64 + ((ty * 4) ^ ((k & 4) << 2))];
            *(float4*)&bv[0] = *(const float4*)&Bs[k * 64 + tx * 4];
#pragma unroll
            for (int i = 0; i < 4; ++i)
#pragma unroll
                for (int j = 0; j < 4; ++j) acc[i][j] = fmaf(a[i], bv[j], acc[i][j]);
        }
    }
#undef LOADA
#pragma unroll
    for (int i = 0; i < 4; ++i) {
        int m = bm + ty * 4 + i;
        float4 o;
        o.x = gelu_np(acc[i][0] + bias[bn + tx * 4 + 0]);
        o.y = gelu_np(acc[i][1] + bias[bn + tx * 4 + 1]);
        o.z = gelu_np(acc[i][2] + bias[bn + tx * 4 + 2]);
        o.w = gelu_np(acc[i][3] + bias[bn + tx * 4 + 3]);
        *(float4*)&out[(size_t)m * N + bn + tx * 4] = o;
    }
}

__global__ void k_d4(const float* __restrict__ h3, const float* __restrict__ w4,
                     const float* __restrict__ b4, float* __restrict__ probs) {
    int m = blockIdx.x * 256 + threadIdx.x;
    if (m >= MS) return;
    float acc = 0.f;
    for (int k = 0; k < 192; ++k) acc = fmaf(h3[(size_t)m * 192 + k], w4[k], acc);
    float pred = acc + b4[0];
    float ef = (float)exp(-(double)pred);
    probs[m] = 1.0f / (1.0f + ef);
}

// fused select (box filter/argmax/masks) + stable sort + outputs
__global__ void k_selsort(const float* __restrict__ probs, const int* __restrict__ gis,
                          float* __restrict__ keep_out, float* __restrict__ rem_out,
                          int* __restrict__ topk, int* __restrict__ keybg) {
    int b = blockIdx.x, t = threadIdx.x;
    __shared__ float pr[256];
    __shared__ double ft[256];
    __shared__ int cxy[2];
    __shared__ float pout[256];
    __shared__ int sf[256];
    __shared__ int ord[256];
    pr[t] = probs[b * 256 + t];
    __syncthreads();
    int X = t >> 4, Y = t & 15;
    double s = 0.0;
    for (int dx = -1; dx <= 1; ++dx)
        for (int dy = -1; dy <= 1; ++dy) {
            int xx = X + dx, yy = Y + dy;
            if (xx >= 0 && xx < 16 && yy >= 0 && yy < 16) s += (double)pr[xx * 16 + yy];
        }
    ft[t] = s;
    __syncthreads();
    if (t == 0) {
        double best = ft[0]; int bi = 0;
        for (int i = 1; i < 256; ++i) if (ft[i] > best) { best = ft[i]; bi = i; }
        cxy[0] = bi >> 4; cxy[1] = bi & 15;
    }
    __syncthreads();
    int cx = cxy[0], cy = cxy[1];
    int ax = X - cx; if (ax < 0) ax = -ax;
    int ay = Y - cy; if (ay < 0) ay = -ay;
    bool m7  = (ax <= 3) && (ay <= 3);
    bool m11 = (ax <= 5) && (ay <= 5);
    int fg = (pr[t] > 0.5f) ? 1 : 0;
    sf[t] = m7 ? fg : 0;
    pout[t] = m11 ? INFINITY : pr[t];
    __syncthreads();
    float pi = pout[t];
    int rank = 0;
    for (int j = 0; j < 256; ++j) {
        float pj = pout[j];
        rank += (pj > pi) || (pj == pi && j < t);
    }
    ord[rank] = t;
    __syncthreads();
    int idx = ord[t];
    int g = gis[b * 256 + idx];
    if (t < NKEEP) {
        keep_out[b * NKEEP + t] = (float)g;
        topk[b * NKEEP + t] = idx;
        keybg[b * NNEW + LTN + t] = (sf[idx] == 0) ? 1 : 0;
    } else {
        rem_out[b * NREM + (t - NKEEP)] = (float)g;
    }
    if (t < LTN) keybg[b * NNEW + t] = 0;
}

// fused gather + write out_x + LN1 -> bf16
__global__ void k_xnew_ln(const float* __restrict__ x, const int* __restrict__ topk,
                          const float* __restrict__ w, const float* __restrict__ b,
                          float* __restrict__ out_x, u16* __restrict__ hn) {
    int row = blockIdx.x, t = threadIdx.x;
    int bb = row / NNEW, r = row - bb * NNEW;
    int src = (r < LTN) ? r : (LTN + topk[bb * NKEEP + (r - LTN)]);
    const float* p = x + (size_t)(bb * NTOK + src) * CCH;
    __shared__ float s1[256], s2[256];
    float v[3]; float a0 = 0.f, a1 = 0.f;
#pragma unroll
    for (int i = 0; i < 3; ++i) { v[i] = p[t + 256 * i]; a0 += v[i]; a1 += v[i] * v[i]; }
#pragma unroll
    for (int i = 0; i < 3; ++i) out_x[(size_t)row * CCH + t + 256 * i] = v[i];
    s1[t] = a0; s2[t] = a1;
    __syncthreads();
    for (int off = 128; off > 0; off >>= 1) {
        if (t < off) { s1[t] += s1[t + off]; s2[t] += s2[t + off]; }
        __syncthreads();
    }
    float mu = s1[0] * (1.0f / CCH);
    float var = s2[0] * (1.0f / CCH) - mu * mu;
    float rstd = rsqrtf(var + 1e-5f);
#pragma unroll
    for (int i = 0; i < 3; ++i) {
        int c = t + 256 * i;
        hn[(size_t)row * CCH + c] = f2bf((v[i] - mu) * rstd * w[c] + b[c]);
    }
}

// ================= transformer: bf16 MFMA path =================

__global__ void k_ln_bf(const float* __restrict__ in, const float* __restrict__ w, const float* __restrict__ b,
                        u16* __restrict__ out) {
    int row = blockIdx.x, t = threadIdx.x;
    __shared__ float s1[256], s2[256];
    const float* p = in + (size_t)row * CCH;
    float v[3]; float a0 = 0.f, a1 = 0.f;
#pragma unroll
    for (int i = 0; i < 3; ++i) { v[i] = p[t + 256 * i]; a0 += v[i]; a1 += v[i] * v[i]; }
    s1[t] = a0; s2[t] = a1;
    __syncthreads();
    for (int off = 128; off > 0; off >>= 1) {
        if (t < off) { s1[t] += s1[t + off]; s2[t] += s2[t + off]; }
        __syncthreads();
    }
    float mu = s1[0] * (1.0f / CCH);
    float var = s2[0] * (1.0f / CCH) - mu * mu;
    float rstd = rsqrtf(var + 1e-5f);
#pragma unroll
    for (int i = 0; i < 3; ++i) {
        int c = t + 256 * i;
        out[(size_t)row * CCH + c] = f2bf((v[i] - mu) * rstd * w[c] + b[c]);
    }
}

// fused prep: 4 weight transposes, one launch
__global__ void k_prep(const float* __restrict__ qkvw, const float* __restrict__ projw,
                       const float* __restrict__ fc1w, const float* __restrict__ fc2w,
                       u16* __restrict__ qkvwT, u16* __restrict__ projwT,
                       u16* __restrict__ fc1wT, u16* __restrict__ fc2wT) {
    int id = blockIdx.x;
    int t = threadIdx.x;
    const float* W; u16* Wt; int K, N, tile;
    if (id < 1728)      { W = qkvw;  Wt = qkvwT;  K = 768;  N = 2304; tile = id; }
    else if (id < 2304) { W = projw; Wt = projwT; K = 768;  N = 768;  tile = id - 1728; }
    else if (id < 4608) { W = fc1w;  Wt = fc1wT;  K = 768;  N = 3072; tile = id - 2304; }
    else                { W = fc2w;  Wt = fc2wT;  K = 3072; N = 768;  tile = id - 4608; }
    int kt = K >> 5;
    int k0 = (tile % kt) * 32, n0 = (tile / kt) * 32;
    __shared__ float tilebuf[32][33];
    int tx = t & 31, ty = t >> 5;
    for (int i = ty; i < 32; i += 8) tilebuf[i][tx] = W[(size_t)(k0 + i) * N + n0 + tx];
    __syncthreads();
    for (int i = ty; i < 32; i += 8) Wt[(size_t)(n0 + i) * K + k0 + tx] = f2bf(tilebuf[tx][i]);
}

// MFMA GEMM: A[M][K] bf16, Bt[N][K] bf16. 128x128 tile, BK=32, 4 waves. XCD-swizzled grid.
// MODE 0: qkv (Q*0.125 + K -> outb[row][1536]; V -> vbuf[row][768] coalesced)
template<int MODE>
__global__ __launch_bounds__(256) void gemm_bf16(const u16* __restrict__ A, const u16* __restrict__ Bt,
                                                 const float* __restrict__ bias, const float* __restrict__ res,
                                                 float* __restrict__ outf, u16* __restrict__ outb,
                                                 u16* __restrict__ vbuf, int N, int K) {
    __shared__ u16 sm[2][2][4096];
    int t = threadIdx.x, lane = t & 63, wid = t >> 6;
    int nwg = gridDim.x * gridDim.y;
    int lin = blockIdx.y * gridDim.x + blockIdx.x;
    int T = xcd_swz(lin, nwg);
    int bx = T % gridDim.x, by = T / gridDim.x;
    int bm = by * 128, bn = bx * 128;
    const u16* pA[2]; const u16* pB[2];
#pragma unroll
    for (int i = 0; i < 2; ++i) {
        int L = wid * 128 + i * 64 + lane;
        int line = L >> 3, sp = L & 7, sl = sp ^ (line & 7);
        int r = (line << 1) | (sl >> 2), k0 = (sl & 3) << 3;
        pA[i] = A + (size_t)(bm + r) * K + k0;
        pB[i] = Bt + (size_t)(bn + r) * K + k0;
    }
    int wr = wid >> 1, wc = wid & 1;
    int l15 = lane & 15, l4 = lane >> 4;
    int rA = wr * 64 + l15, rB = wc * 64 + l15;
    int offA = (rA >> 1) * 128 + (((((rA & 1) << 2) | l4)) ^ ((rA >> 1) & 7)) * 16;
    int offB = (rB >> 1) * 128 + (((((rB & 1) << 2) | l4)) ^ ((rB >> 1) & 7)) * 16;
    f4v zero = {0.f, 0.f, 0.f, 0.f};
    f4v acc[4][4];
#pragma unroll
    for (int i = 0; i < 4; ++i)
#pragma unroll
        for (int j = 0; j < 4; ++j) acc[i][j] = zero;

#define STAGE_G(buf, kt) { \
    u16* da = &sm[buf][0][wid * 1024]; u16* db = &sm[buf][1][wid * 1024]; \
    gl_lds16(pA[0] + (kt) * 32, da); \
    gl_lds16(pA[1] + (kt) * 32, da + 512); \
    gl_lds16(pB[0] + (kt) * 32, db); \
    gl_lds16(pB[1] + (kt) * 32, db + 512); \
}
    int nk = K >> 5;
    STAGE_G(0, 0);
    __syncthreads();
    for (int kt = 0; kt < nk; ++kt) {
        int cur = kt & 1;
        if (kt + 1 < nk) STAGE_G(cur ^ 1, kt + 1);
        const char* bA = (const char*)&sm[cur][0][0];
        const char* bBp = (const char*)&sm[cur][1][0];
        s8v a[4], b[4];
#pragma unroll
        for (int i = 0; i < 4; ++i) {
            a[i] = *(const s8v*)(bA + offA + i * 1024);
            b[i] = *(const s8v*)(bBp + offB + i * 1024);
        }
#pragma unroll
        for (int mf = 0; mf < 4; ++mf)
#pragma unroll
            for (int nf = 0; nf < 4; ++nf)
                acc[mf][nf] = __builtin_amdgcn_mfma_f32_16x16x32_bf16(a[mf], b[nf], acc[mf][nf], 0, 0, 0);
        __syncthreads();
    }
#undef STAGE_G
#pragma unroll
    for (int mf = 0; mf < 4; ++mf)
#pragma unroll
        for (int nf = 0; nf < 4; ++nf)
#pragma unroll
            for (int j = 0; j < 4; ++j) {
                int row = bm + wr * 64 + mf * 16 + l4 * 4 + j;
                int col = bn + wc * 64 + nf * 16 + l15;
                float v = acc[mf][nf][j];
                if (MODE == 0) {
                    if (col < 1536) {
                        if (col < 768) v *= 0.125f;
                        outb[(size_t)row * 1536 + col] = f2bf(v);
                    } else {
                        vbuf[(size_t)row * 768 + (col - 1536)] = f2bf(v);  // coalesced
                    }
                } else if (MODE == 1) {
                    outf[(size_t)row * N + col] = v + bias[col] + res[(size_t)row * N + col];
                } else {
                    float g = v + bias[col];
                    g = 0.5f * g * (1.0f + erff(g * 0.70710678f));
                    outb[(size_t)row * N + col] = f2bf(g);
                }
            }
}

// MFMA attention (XCD-swizzled block map); V transposed during LDS staging
__global__ __launch_bounds__(256) void k_attn2(const u16* __restrict__ qkvQK, const u16* __restrict__ vbuf,
                                               const int* __restrict__ keybg,
                                               float* __restrict__ attn_out, u16* __restrict__ ctx) {
    __shared__ __align__(16) char smem[98560];
    u16* Qs = (u16*)smem;                       // [64][72]
    u16* Ks = (u16*)(smem + 9216);              // [320][72]  (later Vts [64][328])
    u16* Ss = (u16*)(smem + 55296);             // [64][328]  (later OT f32 [64][65])
    int* kb = (int*)(smem + 97280);             // [320]
    float* OT = (float*)Ss;
    u16* Vts = Ks;                              // 64*328*2 = 41984 <= 46080

    int nwg = gridDim.x * gridDim.y;
    int lin = blockIdx.y * gridDim.x + blockIdx.x;
    int T = xcd_swz(lin, nwg);
    int bh = T / 5;
    int q0 = (T - bh * 5) * 64;
    int b = bh / NHH, h = bh % NHH;
    int nq = NNEW - q0; if (nq > 64) nq = 64;
    int t = threadIdx.x, lane = t & 63, wid = t >> 6;
    int l15 = lane & 15, l4 = lane >> 4;
    s8v z = {0, 0, 0, 0, 0, 0, 0, 0};

    {
        int r = t >> 2, c = (t & 3) * 16;
        u16* dst = Qs + r * 72 + c;
        if (r < nq) {
            const u16* src = qkvQK + (size_t)(b * NNEW + q0 + r) * 1536 + h * 64 + c;
            *(s8v*)dst = *(const s8v*)src;
            *(s8v*)(dst + 8) = *(const s8v*)(src + 8);
        } else { *(s8v*)dst = z; *(s8v*)(dst + 8) = z; }
    }
    for (int it = 0; it < 5; ++it) {
        int r = it * 64 + (t >> 2), c = (t & 3) * 16;
        u16* dst = Ks + r * 72 + c;
        if (r < NNEW) {
            const u16* src = qkvQK + (size_t)(b * NNEW + r) * 1536 + 768 + h * 64 + c;
            *(s8v*)dst = *(const s8v*)src;
            *(s8v*)(dst + 8) = *(const s8v*)(src + 8);
        } else { *(s8v*)dst = z; *(s8v*)(dst + 8) = z; }
    }
    for (int i = t; i < 320; i += 256) kb[i] = (i < NNEW) ? keybg[b * NNEW + i] : 1;
    __syncthreads();

    f4v zero = {0.f, 0.f, 0.f, 0.f};
    f4v acc[4][5];
#pragma unroll
    for (int i = 0; i < 4; ++i)
#pragma unroll
        for (int j = 0; j < 5; ++j) acc[i][j] = zero;
#pragma unroll
    for (int ks = 0; ks < 2; ++ks) {
        s8v a[4], bf[5];
#pragma unroll
        for (int mf = 0; mf < 4; ++mf) a[mf] = *(const s8v*)(Qs + (mf * 16 + l15) * 72 + ks * 32 + l4 * 8);
#pragma unroll
        for (int nf = 0; nf < 5; ++nf) bf[nf] = *(const s8v*)(Ks + (wid * 80 + nf * 16 + l15) * 72 + ks * 32 + l4 * 8);
#pragma unroll
        for (int mf = 0; mf < 4; ++mf)
#pragma unroll
            for (int nf = 0; nf < 5; ++nf)
                acc[mf][nf] = __builtin_amdgcn_mfma_f32_16x16x32_bf16(a[mf], bf[nf], acc[mf][nf], 0, 0, 0);
    }
#pragma unroll
    for (int nf = 0; nf < 5; ++nf) {
        int n = wid * 80 + nf * 16 + l15;
        int msk = kb[n];
#pragma unroll
        for (int mf = 0; mf < 4; ++mf)
#pragma unroll
            for (int j = 0; j < 4; ++j) {
                int q = mf * 16 + l4 * 4 + j;
                float v = msk ? -1e9f : acc[mf][nf][j];
                Ss[q * 328 + n] = f2bf(v);
            }
    }
    __syncthreads();

    { // stage V transposed: coalesced global read of V rows, LDS scatter to Vts[d][tok]
        for (int it = 0; it < 5; ++it) {
            int tok = it * 64 + (t >> 2);
            int d0 = (t & 3) * 16;
            if (tok < NNEW) {
                const u16* src = vbuf + (size_t)(b * NNEW + tok) * 768 + h * 64 + d0;
                s8v v0 = *(const s8v*)src;
                s8v v1 = *(const s8v*)(src + 8);
#pragma unroll
                for (int j = 0; j < 8; ++j) Vts[(d0 + j) * 328 + tok] = (u16)v0[j];
#pragma unroll
                for (int j = 0; j < 8; ++j) Vts[(d0 + 8 + j) * 328 + tok] = (u16)v1[j];
            } else if (tok < 320) {
#pragma unroll
                for (int j = 0; j < 16; ++j) Vts[(d0 + j) * 328 + tok] = 0;
            }
        }
    }
    {
        int q = t >> 2, j4 = t & 3;
        u16* row = Ss + q * 328 + j4 * 80;
        float mx = -3e38f;
#pragma unroll
        for (int i = 0; i < 10; ++i) {
            s8v vv = *(const s8v*)(row + i * 8);
#pragma unroll
            for (int e = 0; e < 8; ++e) mx = fmaxf(mx, bf2f((u16)vv[e]));
        }
        mx = fmaxf(mx, __shfl_xor(mx, 1));
        mx = fmaxf(mx, __shfl_xor(mx, 2));
        float sum = 0.f;
#pragma unroll
        for (int i = 0; i < 10; ++i) {
            s8v vv = *(const s8v*)(row + i * 8);
            s8v ov;
#pragma unroll
            for (int e = 0; e < 8; ++e) {
                float ex = expf(bf2f((u16)vv[e]) - mx);
                sum += ex;
                ov[e] = (short)f2bf(ex);
            }
            *(s8v*)(row + i * 8) = ov;
        }
        sum += __shfl_xor(sum, 1);
        sum += __shfl_xor(sum, 2);
        float inv = 1.0f / sum;
#pragma unroll
        for (int i = 0; i < 10; ++i) {
            s8v vv = *(const s8v*)(row + i * 8);
            s8v ov;
            float pf[8];
#pragma unroll
            for (int e = 0; e < 8; ++e) {
                float p = bf2f((u16)vv[e]) * inv;
                pf[e] = p;
                ov[e] = (short)f2bf(p);
            }
            *(s8v*)(row + i * 8) = ov;
            if (q < nq) {
                int n0 = j4 * 80 + i * 8;
                float* dst = attn_out + ((size_t)bh * NNEW + q0 + q) * NNEW + n0;
#pragma unroll
                for (int e = 0; e < 8; ++e) if (n0 + e < NNEW) dst[e] = pf[e];
            }
        }
    }
    __syncthreads();

    f4v o[4];
#pragma unroll
    for (int i = 0; i < 4; ++i) o[i] = zero;
    int dblk = wid * 16;
#pragma unroll
    for (int ks = 0; ks < 10; ++ks) {
        s8v av = *(const s8v*)(Vts + (dblk + l15) * 328 + ks * 32 + l4 * 8);
#pragma unroll
        for (int nf = 0; nf < 4; ++nf) {
            s8v pv = *(const s8v*)(Ss + (nf * 16 + l15) * 328 + ks * 32 + l4 * 8);
            o[nf] = __builtin_amdgcn_mfma_f32_16x16x32_bf16(av, pv, o[nf], 0, 0, 0);
        }
    }
    __syncthreads();
#pragma unroll
    for (int nf = 0; nf < 4; ++nf)
#pragma unroll
        for (int j = 0; j < 4; ++j)
            OT[(dblk + l4 * 4 + j) * 65 + nf * 16 + l15] = o[nf][j];
    __syncthreads();
    {
        int q = t >> 2, c = t & 3;
        if (q < nq) {
            u16 buf[16];
#pragma unroll
            for (int i = 0; i < 16; ++i) buf[i] = f2bf(OT[(c * 16 + i) * 65 + q]);
            u16* dst = ctx + (size_t)(b * NNEW + q0 + q) * CCH + h * 64 + c * 16;
            *(s8v*)dst = *(const s8v*)&buf[0];
            *(s8v*)(dst + 8) = *(const s8v*)&buf[8];
        }
    }
}

// ================= launch =================
extern "C" void kernel_launch(void* const* d_in, const int* in_sizes, int n_in,
                              void* d_out, int out_size, void* d_ws, size_t ws_size,
                              hipStream_t stream) {
    const float* x     = (const float*)d_in[0];
    const int*   gis   = (const int*)d_in[2];
    const float* mask  = (const float*)d_in[3];
    const float* ln1w  = (const float*)d_in[4];
    const float* ln1b  = (const float*)d_in[5];
    const float* qkvw  = (const float*)d_in[6];
    const float* projw = (const float*)d_in[7];
    const float* projb = (const float*)d_in[8];
    const float* ln2w  = (const float*)d_in[9];
    const float* ln2b  = (const float*)d_in[10];
    const float* fc1w  = (const float*)d_in[11];
    const float* fc1b  = (const float*)d_in[12];
    const float* fc2w  = (const float*)d_in[13];
    const float* fc2b  = (const float*)d_in[14];
    const float* d1w   = (const float*)d_in[15];
    const float* d1b   = (const float*)d_in[16];
    const float* d2w   = (const float*)d_in[17];
    const float* d2b   = (const float*)d_in[18];
    const float* d3w   = (const float*)d_in[19];
    const float* d3b   = (const float*)d_in[20];
    const float* d4w   = (const float*)d_in[21];
    const float* d4b   = (const float*)d_in[22];

    float* out_x    = (float*)d_out;
    float* out_keep = out_x + 7569408;
    float* out_rem  = out_keep + 5760;
    float* out_attn = out_rem + 2432;

    char* ws = (char*)d_ws;
    u16* hn_bf  = (u16*)(ws);
    u16* qkvQK  = (u16*)(ws + 15138816);
    u16* vbuf   = (u16*)(ws + 45416448);         // V [9856][768] bf16, coalesced
    u16* fc1_bf = (u16*)(ws);
    u16* ctx_bf = (u16*)(ws + 60751872);
    u16* qkvwT  = (u16*)(ws + 75890688);
    u16* projwT = (u16*)(ws + 79429632);
    u16* fc1wT  = (u16*)(ws + 80609280);
    u16* fc2wT  = (u16*)(ws + 85327872);
    char* misc  = ws + 90046464;
    float* rep0  = (float*)(misc + 0 * 262144);
    float* rep1  = (float*)(misc + 1 * 262144);
    float* probs = (float*)(misc + 2 * 262144);
    int*   topk  = (int*)(misc + 5 * 262144);
    int*   keybg = (int*)(misc + 6 * 262144);
    size_t required = 90046464ull + 7ull * 262144ull;
    if (ws_size < required) {
        k_fail<<<1, 1, 0, stream>>>((float*)d_out, (float)(ws_size / 1048576.0));
        return;
    }

    float* h1 = (float*)out_attn;
    float* h2 = h1 + 8192 * 768;
    float* h3 = h2 + 8192 * 384;

    k_prep<<<6912, 256, 0, stream>>>(qkvw, projw, fc1w, fc2w, qkvwT, projwT, fc1wT, fc2wT);

    k_reps<<<BB, 256, 0, stream>>>(x, mask, rep0, rep1);
    gemm_exact<1><<<dim3(12, 128), 256, 0, stream>>>(x, rep0, rep1, d1w, d1b, h1, 768, 2304);
    gemm_exact<0><<<dim3(6, 128), 256, 0, stream>>>(h1, nullptr, nullptr, d2w, d2b, h2, 384, 768);
    gemm_exact<0><<<dim3(3, 128), 256, 0, stream>>>(h2, nullptr, nullptr, d3w, d3b, h3, 192, 384);
    k_d4<<<MS / 256, 256, 0, stream>>>(h3, d4w, d4b, probs);
    k_selsort<<<BB, 256, 0, stream>>>(probs, gis, out_keep, out_rem, topk, keybg);
    k_xnew_ln<<<MN, 256, 0, stream>>>(x, topk, ln1w, ln1b, out_x, hn_bf);

    gemm_bf16<0><<<dim3(18, 77), 256, 0, stream>>>(hn_bf, qkvwT, nullptr, nullptr, nullptr, qkvQK, vbuf, 2304, 768);
    k_attn2<<<dim3(5, 384), 256, 0, stream>>>(qkvQK, vbuf, keybg, out_attn, ctx_bf);
    gemm_bf16<1><<<dim3(6, 77), 256, 0, stream>>>(ctx_bf, projwT, projb, out_x, out_x, nullptr, nullptr, 768, 768);
    k_ln_bf<<<MN, 256, 0, stream>>>(out_x, ln2w, ln2b, ctx_bf);
    gemm_bf16<2><<<dim3(24, 77), 256, 0, stream>>>(ctx_bf, fc1wT, fc1b, nullptr, nullptr, fc1_bf, nullptr, 3072, 768);
    gemm_bf16<1><<<dim3(6, 77), 256, 0, stream>>>(fc1_bf, fc2wT, fc2b, out_x, out_x, nullptr, nullptr, 768, 3072);
}